// Round 1
// baseline (2645.545 us; speedup 1.0000x reference)
//
#include <hip/hip_runtime.h>
#include <hip/hip_bf16.h>

#define N_NODES 100000
#define N_EDGES 1600000
#define IN_DIM 128
#define HID 512
#define NCLS 64

// ---------- helpers ----------
__device__ inline float bf2f(unsigned short b) {
    unsigned int u = ((unsigned int)b) << 16;
    return __builtin_bit_cast(float, u);
}
__device__ inline unsigned short f2bf(float f) {
    unsigned int u = __builtin_bit_cast(unsigned int, f);
    unsigned int lsb = (u >> 16) & 1u;
    u += 0x7fffu + lsb;
    return (unsigned short)(u >> 16);
}
__device__ inline float ldf(float v) { return v; }
__device__ inline float ldf(unsigned short v) { return bf2f(v); }

__device__ inline void st4(unsigned short* p, float v0, float v1, float v2, float v3) {
    uint2 u;
    u.x = (unsigned)f2bf(v0) | ((unsigned)f2bf(v1) << 16);
    u.y = (unsigned)f2bf(v2) | ((unsigned)f2bf(v3) << 16);
    *reinterpret_cast<uint2*>(p) = u;
}
__device__ inline void st4(float* p, float v0, float v1, float v2, float v3) {
    *reinterpret_cast<float4*>(p) = make_float4(v0, v1, v2, v3);
}

__device__ inline float selu_f(float x) {
    const float scale = 1.0507009873554805f;
    const float alpha = 1.6732632423543772f;
    return x > 0.f ? scale * x : scale * alpha * (__expf(x) - 1.f);
}

// ---------- CSR build ----------
__global__ __launch_bounds__(256) void k_deg(const int* __restrict__ dst, int* __restrict__ deg) {
    int e = blockIdx.x * 256 + threadIdx.x;
    if (e < N_EDGES) atomicAdd(&deg[dst[e]], 1);
}

__global__ __launch_bounds__(1024) void k_scan(const int* __restrict__ deg, int* __restrict__ off,
                                               int* __restrict__ pos) {
    __shared__ int sd[1024];
    const int t = threadIdx.x;
    int running = 0;
    for (int base = 0; base < N_NODES; base += 4096) {
        int i0 = base + t * 4;
        int v0 = (i0 + 0 < N_NODES) ? deg[i0 + 0] : 0;
        int v1 = (i0 + 1 < N_NODES) ? deg[i0 + 1] : 0;
        int v2 = (i0 + 2 < N_NODES) ? deg[i0 + 2] : 0;
        int v3 = (i0 + 3 < N_NODES) ? deg[i0 + 3] : 0;
        int sum = v0 + v1 + v2 + v3;
        sd[t] = sum;
        __syncthreads();
        for (int o = 1; o < 1024; o <<= 1) {
            int tv = (t >= o) ? sd[t - o] : 0;
            __syncthreads();
            sd[t] += tv;
            __syncthreads();
        }
        int excl = running + sd[t] - sum;
        if (i0 + 0 < N_NODES) { off[i0 + 0] = excl; pos[i0 + 0] = excl; }
        excl += v0;
        if (i0 + 1 < N_NODES) { off[i0 + 1] = excl; pos[i0 + 1] = excl; }
        excl += v1;
        if (i0 + 2 < N_NODES) { off[i0 + 2] = excl; pos[i0 + 2] = excl; }
        excl += v2;
        if (i0 + 3 < N_NODES) { off[i0 + 3] = excl; pos[i0 + 3] = excl; }
        running += sd[1023];
        __syncthreads();
    }
    if (t == 0) off[N_NODES] = running;
}

__global__ __launch_bounds__(256) void k_fill(const int* __restrict__ src, const int* __restrict__ dst,
                                              int* __restrict__ pos, int* __restrict__ adj) {
    int e = blockIdx.x * 256 + threadIdx.x;
    if (e < N_EDGES) {
        int p = atomicAdd(&pos[dst[e]], 1);
        adj[p] = src[e];
    }
}

// ---------- aggregation (gather) ----------
__global__ __launch_bounds__(256) void k_agg1(const float* __restrict__ x, const int* __restrict__ off,
                                              const int* __restrict__ adj, float* __restrict__ A1) {
    int w = (blockIdx.x * 256 + threadIdx.x) >> 6;
    if (w >= N_NODES) return;
    int lane = threadIdx.x & 63;
    float2 v = ((const float2*)(x + (size_t)w * IN_DIM))[lane];
    float s0 = v.x, s1 = v.y;
    int e0 = off[w], e1 = off[w + 1];
    for (int e = e0; e < e1; ++e) {
        int j = adj[e];
        float2 u = ((const float2*)(x + (size_t)j * IN_DIM))[lane];
        s0 += u.x; s1 += u.y;
    }
    ((float2*)(A1 + (size_t)w * IN_DIM))[lane] = make_float2(s0, s1);
}

__global__ __launch_bounds__(256) void k_agg2(const unsigned short* __restrict__ h, const int* __restrict__ off,
                                              const int* __restrict__ adj, unsigned short* __restrict__ outb) {
    int w = (blockIdx.x * 256 + threadIdx.x) >> 6;
    if (w >= N_NODES) return;
    int lane = threadIdx.x & 63;
    float s[8];
    uint4 v = ((const uint4*)(h + (size_t)w * HID))[lane];
    s[0] = bf2f((unsigned short)(v.x & 0xffff)); s[1] = bf2f((unsigned short)(v.x >> 16));
    s[2] = bf2f((unsigned short)(v.y & 0xffff)); s[3] = bf2f((unsigned short)(v.y >> 16));
    s[4] = bf2f((unsigned short)(v.z & 0xffff)); s[5] = bf2f((unsigned short)(v.z >> 16));
    s[6] = bf2f((unsigned short)(v.w & 0xffff)); s[7] = bf2f((unsigned short)(v.w >> 16));
    int e0 = off[w], e1 = off[w + 1];
    for (int e = e0; e < e1; ++e) {
        int j = adj[e];
        uint4 u = ((const uint4*)(h + (size_t)j * HID))[lane];
        s[0] += bf2f((unsigned short)(u.x & 0xffff)); s[1] += bf2f((unsigned short)(u.x >> 16));
        s[2] += bf2f((unsigned short)(u.y & 0xffff)); s[3] += bf2f((unsigned short)(u.y >> 16));
        s[4] += bf2f((unsigned short)(u.z & 0xffff)); s[5] += bf2f((unsigned short)(u.z >> 16));
        s[6] += bf2f((unsigned short)(u.w & 0xffff)); s[7] += bf2f((unsigned short)(u.w >> 16));
    }
    uint4 o;
    o.x = (unsigned)f2bf(s[0]) | ((unsigned)f2bf(s[1]) << 16);
    o.y = (unsigned)f2bf(s[2]) | ((unsigned)f2bf(s[3]) << 16);
    o.z = (unsigned)f2bf(s[4]) | ((unsigned)f2bf(s[5]) << 16);
    o.w = (unsigned)f2bf(s[6]) | ((unsigned)f2bf(s[7]) << 16);
    ((uint4*)(outb + (size_t)w * HID))[lane] = o;
}

// ---------- GEMM: Out[M,NC] = act(A[M,K] @ W[K,NC] + bias) ----------
template <int K, int NC, int ACT, typename TIN, typename TOUT>
__global__ __launch_bounds__(256) void k_gemm(const TIN* __restrict__ A, const float* __restrict__ W,
                                              const float* __restrict__ bias, TOUT* __restrict__ Out,
                                              int M) {
    constexpr int BM = 64, BN = 64, BK = 16;
    __shared__ float As[BK][BM + 4];
    __shared__ float Ws[BK][BN + 4];
    const int tid = threadIdx.x;
    const int trow = tid >> 4;   // 0..15 -> rows trow*4 .. +3
    const int tcol = tid & 15;   // cols tcol*4 .. +3
    const int rowbase = blockIdx.x * BM;
    const int colbase = blockIdx.y * BN;
    float acc[4][4] = {{0.f, 0.f, 0.f, 0.f}, {0.f, 0.f, 0.f, 0.f},
                       {0.f, 0.f, 0.f, 0.f}, {0.f, 0.f, 0.f, 0.f}};
    for (int k0 = 0; k0 < K; k0 += BK) {
#pragma unroll
        for (int i = 0; i < 4; ++i) {
            int idx = tid + i * 256;
            int r = idx >> 4;
            int kk = idx & 15;
            int gr = rowbase + r;
            float v = 0.f;
            if (gr < M) v = ldf(A[(size_t)gr * K + k0 + kk]);
            As[kk][r] = v;
        }
#pragma unroll
        for (int i = 0; i < 4; ++i) {
            int idx = tid + i * 256;
            int kk = idx >> 6;
            int c = idx & 63;
            Ws[kk][c] = W[(size_t)(k0 + kk) * NC + colbase + c];
        }
        __syncthreads();
#pragma unroll
        for (int kk = 0; kk < BK; ++kk) {
            float4 av = *reinterpret_cast<const float4*>(&As[kk][trow * 4]);
            float4 wv = *reinterpret_cast<const float4*>(&Ws[kk][tcol * 4]);
            float a[4] = {av.x, av.y, av.z, av.w};
            float w[4] = {wv.x, wv.y, wv.z, wv.w};
#pragma unroll
            for (int i = 0; i < 4; ++i)
#pragma unroll
                for (int j = 0; j < 4; ++j) acc[i][j] += a[i] * w[j];
        }
        __syncthreads();
    }
    float b[4];
#pragma unroll
    for (int j = 0; j < 4; ++j) b[j] = bias[colbase + tcol * 4 + j];
#pragma unroll
    for (int i = 0; i < 4; ++i) {
        int gr = rowbase + trow * 4 + i;
        if (gr >= M) continue;
        float v[4];
#pragma unroll
        for (int j = 0; j < 4; ++j) {
            float t = acc[i][j] + b[j];
            v[j] = (ACT == 0) ? fmaxf(t, 0.f) : selu_f(t);
        }
        st4(&Out[(size_t)gr * NC + colbase + tcol * 4], v[0], v[1], v[2], v[3]);
    }
}

// ---------- BatchNorm ----------
__global__ __launch_bounds__(256) void k_bnstats_h(const unsigned short* __restrict__ C,
                                                   float* __restrict__ sums) {
    int t = threadIdx.x;
    float s0 = 0, q0 = 0, s1 = 0, q1 = 0;
    for (int r = blockIdx.x; r < N_NODES; r += gridDim.x) {
        const unsigned short* row = C + (size_t)r * HID;
        float a = bf2f(row[t]);
        float c = bf2f(row[t + 256]);
        s0 += a; q0 += a * a;
        s1 += c; q1 += c * c;
    }
    atomicAdd(&sums[t], s0);
    atomicAdd(&sums[t + 256], s1);
    atomicAdd(&sums[HID + t], q0);
    atomicAdd(&sums[HID + t + 256], q1);
}

__global__ void k_bnprep(float* __restrict__ bn, const float* __restrict__ gamma,
                         const float* __restrict__ beta, int C, float invn) {
    int c = threadIdx.x + blockIdx.x * blockDim.x;
    if (c >= C) return;
    float mu = bn[c] * invn;
    float var = bn[C + c] * invn - mu * mu;
    float sc = gamma[c] * rsqrtf(var + 1e-5f);
    bn[2 * C + c] = sc;
    bn[3 * C + c] = beta[c] - mu * sc;
}

__global__ __launch_bounds__(256) void k_bnapply(unsigned short* __restrict__ C,
                                                 const float* __restrict__ bn) {
    size_t g = (size_t)blockIdx.x * 256 + threadIdx.x;
    size_t total = (size_t)N_NODES * HID / 8;
    if (g >= total) return;
    int cbase = (int)((g * 8) & (HID - 1));
    const float* scale = bn + 2 * HID;
    const float* shift = bn + 3 * HID;
    uint4 v = ((const uint4*)C)[g];
    float r[8];
    r[0] = bf2f((unsigned short)(v.x & 0xffff)); r[1] = bf2f((unsigned short)(v.x >> 16));
    r[2] = bf2f((unsigned short)(v.y & 0xffff)); r[3] = bf2f((unsigned short)(v.y >> 16));
    r[4] = bf2f((unsigned short)(v.z & 0xffff)); r[5] = bf2f((unsigned short)(v.z >> 16));
    r[6] = bf2f((unsigned short)(v.w & 0xffff)); r[7] = bf2f((unsigned short)(v.w >> 16));
#pragma unroll
    for (int j = 0; j < 8; ++j) r[j] = r[j] * scale[cbase + j] + shift[cbase + j];
    uint4 o;
    o.x = (unsigned)f2bf(r[0]) | ((unsigned)f2bf(r[1]) << 16);
    o.y = (unsigned)f2bf(r[2]) | ((unsigned)f2bf(r[3]) << 16);
    o.z = (unsigned)f2bf(r[4]) | ((unsigned)f2bf(r[5]) << 16);
    o.w = (unsigned)f2bf(r[6]) | ((unsigned)f2bf(r[7]) << 16);
    ((uint4*)C)[g] = o;
}

__global__ __launch_bounds__(256) void k_bnstats_o(const float* __restrict__ O,
                                                   float* __restrict__ bn2) {
    int t = threadIdx.x;
    int c = t & 63;
    int rr = t >> 6;
    float s = 0, q = 0;
    for (int r = blockIdx.x * 4 + rr; r < N_NODES; r += gridDim.x * 4) {
        float a = O[(size_t)r * NCLS + c];
        s += a; q += a * a;
    }
    atomicAdd(&bn2[c], s);
    atomicAdd(&bn2[NCLS + c], q);
}

__global__ __launch_bounds__(256) void k_softmax(float* __restrict__ O, const float* __restrict__ bn2) {
    int w = (blockIdx.x * 256 + threadIdx.x) >> 6;
    if (w >= N_NODES) return;
    int lane = threadIdx.x & 63;
    float z = O[(size_t)w * NCLS + lane] * bn2[2 * NCLS + lane] + bn2[3 * NCLS + lane];
    float m = z;
#pragma unroll
    for (int o = 32; o > 0; o >>= 1) m = fmaxf(m, __shfl_xor(m, o));
    float e = __expf(z - m);
    float s = e;
#pragma unroll
    for (int o = 32; o > 0; o >>= 1) s += __shfl_xor(s, o);
    O[(size_t)w * NCLS + lane] = e / s;
}

// ---------- launch ----------
extern "C" void kernel_launch(void* const* d_in, const int* in_sizes, int n_in,
                              void* d_out, int out_size, void* d_ws, size_t ws_size,
                              hipStream_t stream) {
    const float* x = (const float*)d_in[0];
    const int* edge = (const int*)d_in[1];
    const int* srcp = edge;
    const int* dstp = edge + N_EDGES;
    const float* W1a = (const float*)d_in[9];
    const float* b1a = (const float*)d_in[10];
    const float* W1b = (const float*)d_in[11];
    const float* b1b = (const float*)d_in[12];
    const float* gamma1 = (const float*)d_in[13];
    const float* beta1 = (const float*)d_in[14];
    const float* W2a = (const float*)d_in[15];
    const float* b2a = (const float*)d_in[16];
    const float* W2b = (const float*)d_in[17];
    const float* b2b = (const float*)d_in[18];
    const float* gamma2 = (const float*)d_in[19];
    const float* beta2 = (const float*)d_in[20];
    float* out = (float*)d_out;

    char* ws = (char*)d_ws;
    size_t o = 0;
    auto alloc = [&](size_t bytes) -> char* {
        char* p = ws + o;
        o = (o + bytes + 255) & ~(size_t)255;
        return p;
    };
    int* off = (int*)alloc((N_NODES + 1) * sizeof(int));
    int* deg = (int*)alloc(N_NODES * sizeof(int));
    int* pos = (int*)alloc(N_NODES * sizeof(int));
    int* adj = (int*)alloc(N_EDGES * sizeof(int));
    float* bn1 = (float*)alloc(4 * HID * sizeof(float));
    float* bn2 = (float*)alloc(4 * NCLS * sizeof(float));
    float* A1 = (float*)alloc((size_t)N_NODES * IN_DIM * sizeof(float));
    unsigned short* B = (unsigned short*)alloc((size_t)N_NODES * HID * sizeof(unsigned short));
    unsigned short* C = (unsigned short*)alloc((size_t)N_NODES * HID * sizeof(unsigned short));

    hipMemsetAsync(deg, 0, N_NODES * sizeof(int), stream);
    hipMemsetAsync(bn1, 0, 2 * HID * sizeof(float), stream);
    hipMemsetAsync(bn2, 0, 2 * NCLS * sizeof(float), stream);

    int eb = (N_EDGES + 255) / 256;
    k_deg<<<eb, 256, 0, stream>>>(dstp, deg);
    k_scan<<<1, 1024, 0, stream>>>(deg, off, pos);
    k_fill<<<eb, 256, 0, stream>>>(srcp, dstp, pos, adj);

    int nwb = (N_NODES * 64 + 255) / 256;  // one wave per node
    k_agg1<<<nwb, 256, 0, stream>>>(x, off, adj, A1);

    dim3 g1((N_NODES + 63) / 64, HID / 64);
    k_gemm<IN_DIM, HID, 0, float, unsigned short><<<g1, 256, 0, stream>>>(A1, W1a, b1a, B, N_NODES);
    k_gemm<HID, HID, 1, unsigned short, unsigned short><<<g1, 256, 0, stream>>>(B, W1b, b1b, C, N_NODES);

    k_bnstats_h<<<1024, 256, 0, stream>>>(C, bn1);
    k_bnprep<<<2, 256, 0, stream>>>(bn1, gamma1, beta1, HID, 1.0f / N_NODES);
    k_bnapply<<<(N_NODES * HID / 8 + 255) / 256, 256, 0, stream>>>(C, bn1);

    k_agg2<<<nwb, 256, 0, stream>>>(C, off, adj, B);

    k_gemm<HID, HID, 0, unsigned short, unsigned short><<<g1, 256, 0, stream>>>(B, W2a, b2a, C, N_NODES);
    dim3 g2((N_NODES + 63) / 64, 1);
    k_gemm<HID, NCLS, 1, unsigned short, float><<<g2, 256, 0, stream>>>(C, W2b, b2b, out, N_NODES);

    k_bnstats_o<<<1024, 256, 0, stream>>>(out, bn2);
    k_bnprep<<<1, 64, 0, stream>>>(bn2, gamma2, beta2, NCLS, 1.0f / N_NODES);
    k_softmax<<<nwb, 256, 0, stream>>>(out, bn2);
}

// Round 2
// 1312.826 us; speedup vs baseline: 2.0152x; 2.0152x over previous
//
#include <hip/hip_runtime.h>
#include <hip/hip_bf16.h>

#define N_NODES 100000
#define N_EDGES 1600000
#define IN_DIM 128
#define HID 512
#define NCLS 64

typedef __attribute__((ext_vector_type(8))) short bf16x8;
typedef __attribute__((ext_vector_type(4))) float f32x4;

// ---------- helpers ----------
__device__ inline float bf2f(unsigned short b) {
    unsigned int u = ((unsigned int)b) << 16;
    return __builtin_bit_cast(float, u);
}
__device__ inline unsigned short f2bf(float f) {
    unsigned int u = __builtin_bit_cast(unsigned int, f);
    unsigned int lsb = (u >> 16) & 1u;
    u += 0x7fffu + lsb;
    return (unsigned short)(u >> 16);
}
__device__ inline float selu_f(float x) {
    const float scale = 1.0507009873554805f;
    const float alpha = 1.6732632423543772f;
    return x > 0.f ? scale * x : scale * alpha * (__expf(x) - 1.f);
}
__device__ inline void stb(float* p, float v) { *p = v; }
__device__ inline void stb(unsigned short* p, float v) { *p = f2bf(v); }

// ---------- CSR build ----------
__global__ __launch_bounds__(256) void k_deg(const int* __restrict__ dst, int* __restrict__ deg) {
    int e = blockIdx.x * 256 + threadIdx.x;
    if (e < N_EDGES) atomicAdd(&deg[dst[e]], 1);
}

__global__ __launch_bounds__(1024) void k_scan(const int* __restrict__ deg, int* __restrict__ off,
                                               int* __restrict__ pos) {
    __shared__ int sd[1024];
    const int t = threadIdx.x;
    int running = 0;
    for (int base = 0; base < N_NODES; base += 4096) {
        int i0 = base + t * 4;
        int v0 = (i0 + 0 < N_NODES) ? deg[i0 + 0] : 0;
        int v1 = (i0 + 1 < N_NODES) ? deg[i0 + 1] : 0;
        int v2 = (i0 + 2 < N_NODES) ? deg[i0 + 2] : 0;
        int v3 = (i0 + 3 < N_NODES) ? deg[i0 + 3] : 0;
        int sum = v0 + v1 + v2 + v3;
        sd[t] = sum;
        __syncthreads();
        for (int o = 1; o < 1024; o <<= 1) {
            int tv = (t >= o) ? sd[t - o] : 0;
            __syncthreads();
            sd[t] += tv;
            __syncthreads();
        }
        int excl = running + sd[t] - sum;
        if (i0 + 0 < N_NODES) { off[i0 + 0] = excl; pos[i0 + 0] = excl; }
        excl += v0;
        if (i0 + 1 < N_NODES) { off[i0 + 1] = excl; pos[i0 + 1] = excl; }
        excl += v1;
        if (i0 + 2 < N_NODES) { off[i0 + 2] = excl; pos[i0 + 2] = excl; }
        excl += v2;
        if (i0 + 3 < N_NODES) { off[i0 + 3] = excl; pos[i0 + 3] = excl; }
        running += sd[1023];
        __syncthreads();
    }
    if (t == 0) off[N_NODES] = running;
}

__global__ __launch_bounds__(256) void k_fill(const int* __restrict__ src, const int* __restrict__ dst,
                                              int* __restrict__ pos, int* __restrict__ adj) {
    int e = blockIdx.x * 256 + threadIdx.x;
    if (e < N_EDGES) {
        int p = atomicAdd(&pos[dst[e]], 1);
        adj[p] = src[e];
    }
}

// ---------- weight pack: W[K][NC] f32 -> fragment-ready bf16 ----------
// Wp[((nt*(K/32)+kt)*64 + lane)*8 + j] = bf16(W[kt*32 + (lane>>4)*8 + j][nt*16 + (lane&15)])
__global__ __launch_bounds__(256) void k_pack(const float* __restrict__ W,
                                              unsigned short* __restrict__ Wp, int K, int NC) {
    int idx = blockIdx.x * 256 + threadIdx.x;
    if (idx >= K * NC) return;
    int j = idx & 7;
    int l = (idx >> 3) & 63;
    int t = idx >> 9;
    int KT = K >> 5;
    int kt = t % KT;
    int nt = t / KT;
    int k = kt * 32 + (l >> 4) * 8 + j;
    int n = nt * 16 + (l & 15);
    Wp[idx] = f2bf(W[(size_t)k * NC + n]);
}

// ---------- aggregation (gather) ----------
__global__ __launch_bounds__(256) void k_agg1(const float* __restrict__ x, const int* __restrict__ off,
                                              const int* __restrict__ adj, unsigned short* __restrict__ A1) {
    int w = (blockIdx.x * 256 + threadIdx.x) >> 6;
    if (w >= N_NODES) return;
    int lane = threadIdx.x & 63;
    float2 v = ((const float2*)(x + (size_t)w * IN_DIM))[lane];
    float s0 = v.x, s1 = v.y;
    int e0 = off[w], e1 = off[w + 1];
    for (int e = e0; e < e1; ++e) {
        int j = adj[e];
        float2 u = ((const float2*)(x + (size_t)j * IN_DIM))[lane];
        s0 += u.x; s1 += u.y;
    }
    ((unsigned*)(A1 + (size_t)w * IN_DIM))[lane] = (unsigned)f2bf(s0) | ((unsigned)f2bf(s1) << 16);
}

// agg2 with fused BN1: out = scale * (sum_{j in {w} u N(w)} c_j) + (deg+1)*shift
__global__ __launch_bounds__(256) void k_agg2(const unsigned short* __restrict__ h, const int* __restrict__ off,
                                              const int* __restrict__ adj, const float* __restrict__ bn,
                                              unsigned short* __restrict__ outb) {
    int w = (blockIdx.x * 256 + threadIdx.x) >> 6;
    if (w >= N_NODES) return;
    int lane = threadIdx.x & 63;
    float s[8];
    uint4 v = ((const uint4*)(h + (size_t)w * HID))[lane];
    s[0] = bf2f((unsigned short)(v.x & 0xffff)); s[1] = bf2f((unsigned short)(v.x >> 16));
    s[2] = bf2f((unsigned short)(v.y & 0xffff)); s[3] = bf2f((unsigned short)(v.y >> 16));
    s[4] = bf2f((unsigned short)(v.z & 0xffff)); s[5] = bf2f((unsigned short)(v.z >> 16));
    s[6] = bf2f((unsigned short)(v.w & 0xffff)); s[7] = bf2f((unsigned short)(v.w >> 16));
    int e0 = off[w], e1 = off[w + 1];
    for (int e = e0; e < e1; ++e) {
        int j = adj[e];
        uint4 u = ((const uint4*)(h + (size_t)j * HID))[lane];
        s[0] += bf2f((unsigned short)(u.x & 0xffff)); s[1] += bf2f((unsigned short)(u.x >> 16));
        s[2] += bf2f((unsigned short)(u.y & 0xffff)); s[3] += bf2f((unsigned short)(u.y >> 16));
        s[4] += bf2f((unsigned short)(u.z & 0xffff)); s[5] += bf2f((unsigned short)(u.z >> 16));
        s[6] += bf2f((unsigned short)(u.w & 0xffff)); s[7] += bf2f((unsigned short)(u.w >> 16));
    }
    float dp1 = (float)(e1 - e0 + 1);
    int cb = lane * 8;
    const float* scale = bn + 2 * HID + cb;
    const float* shift = bn + 3 * HID + cb;
    float r[8];
#pragma unroll
    for (int j = 0; j < 8; ++j) r[j] = s[j] * scale[j] + dp1 * shift[j];
    uint4 o;
    o.x = (unsigned)f2bf(r[0]) | ((unsigned)f2bf(r[1]) << 16);
    o.y = (unsigned)f2bf(r[2]) | ((unsigned)f2bf(r[3]) << 16);
    o.z = (unsigned)f2bf(r[4]) | ((unsigned)f2bf(r[5]) << 16);
    o.w = (unsigned)f2bf(r[6]) | ((unsigned)f2bf(r[7]) << 16);
    ((uint4*)(outb + (size_t)w * HID))[lane] = o;
}

// ---------- MFMA GEMM: Out[M,NC] = act(A[M,K] @ W[K,NC] + bias) ----------
// A: bf16 row-major. Wp: fragment-packed bf16. Per-wave tile 32x64 (2x4 accs).
template <int K, int NC, int ACT, int WAVES_M, int WAVES_N, typename TOUT>
__global__ __launch_bounds__(WAVES_M * WAVES_N * 64) void k_mgemm(
    const unsigned short* __restrict__ A, const unsigned short* __restrict__ Wp,
    const float* __restrict__ bias, TOUT* __restrict__ Out, int M) {
    const int tid = threadIdx.x;
    const int lane = tid & 63;
    const int w = tid >> 6;
    const int wm = w / WAVES_N;
    const int wn = w % WAVES_N;
    const int l15 = lane & 15;
    const int lg = lane >> 4;
    const int rowbase = blockIdx.x * (32 * WAVES_M) + wm * 32;
    const int colbase = blockIdx.y * (64 * WAVES_N) + wn * 64;
    int r0 = rowbase + l15; if (r0 > M - 1) r0 = M - 1;
    int r1 = rowbase + 16 + l15; if (r1 > M - 1) r1 = M - 1;
    const unsigned short* pa0 = A + (size_t)r0 * K + lg * 8;
    const unsigned short* pa1 = A + (size_t)r1 * K + lg * 8;
    const unsigned short* pw = Wp + (size_t)(colbase >> 4) * (K / 32) * 512 + lane * 8;

    f32x4 acc[2][4];
#pragma unroll
    for (int i = 0; i < 2; ++i)
#pragma unroll
        for (int j = 0; j < 4; ++j) acc[i][j] = (f32x4)0.f;

#pragma unroll 2
    for (int kt = 0; kt < K / 32; ++kt) {
        bf16x8 a0 = *(const bf16x8*)(pa0 + kt * 32);
        bf16x8 a1 = *(const bf16x8*)(pa1 + kt * 32);
#pragma unroll
        for (int ni = 0; ni < 4; ++ni) {
            bf16x8 bv = *(const bf16x8*)(pw + (ni * (K / 32) + kt) * 512);
            acc[0][ni] = __builtin_amdgcn_mfma_f32_16x16x32_bf16(a0, bv, acc[0][ni], 0, 0, 0);
            acc[1][ni] = __builtin_amdgcn_mfma_f32_16x16x32_bf16(a1, bv, acc[1][ni], 0, 0, 0);
        }
    }

#pragma unroll
    for (int ni = 0; ni < 4; ++ni) {
        int c = colbase + ni * 16 + l15;
        float bv = bias[c];
#pragma unroll
        for (int mi = 0; mi < 2; ++mi) {
#pragma unroll
            for (int r = 0; r < 4; ++r) {
                int row = rowbase + mi * 16 + lg * 4 + r;
                if (row < M) {
                    float t = acc[mi][ni][r] + bv;
                    t = (ACT == 0) ? fmaxf(t, 0.f) : selu_f(t);
                    stb(&Out[(size_t)row * NC + c], t);
                }
            }
        }
    }
}

// ---------- BatchNorm stats ----------
__global__ __launch_bounds__(256) void k_bnstats_h(const unsigned short* __restrict__ C,
                                                   float* __restrict__ sums) {
    int t = threadIdx.x;
    float s0 = 0, q0 = 0, s1 = 0, q1 = 0;
    for (int r = blockIdx.x; r < N_NODES; r += gridDim.x) {
        const unsigned short* row = C + (size_t)r * HID;
        float a = bf2f(row[t]);
        float c = bf2f(row[t + 256]);
        s0 += a; q0 += a * a;
        s1 += c; q1 += c * c;
    }
    atomicAdd(&sums[t], s0);
    atomicAdd(&sums[t + 256], s1);
    atomicAdd(&sums[HID + t], q0);
    atomicAdd(&sums[HID + t + 256], q1);
}

__global__ void k_bnprep(float* __restrict__ bn, const float* __restrict__ gamma,
                         const float* __restrict__ beta, int C, float invn) {
    int c = threadIdx.x + blockIdx.x * blockDim.x;
    if (c >= C) return;
    float mu = bn[c] * invn;
    float var = bn[C + c] * invn - mu * mu;
    float sc = gamma[c] * rsqrtf(var + 1e-5f);
    bn[2 * C + c] = sc;
    bn[3 * C + c] = beta[c] - mu * sc;
}

__global__ __launch_bounds__(256) void k_bnstats_o(const float* __restrict__ O,
                                                   float* __restrict__ bn2) {
    int t = threadIdx.x;
    int c = t & 63;
    int rr = t >> 6;
    float s = 0, q = 0;
    for (int r = blockIdx.x * 4 + rr; r < N_NODES; r += gridDim.x * 4) {
        float a = O[(size_t)r * NCLS + c];
        s += a; q += a * a;
    }
    atomicAdd(&bn2[c], s);
    atomicAdd(&bn2[NCLS + c], q);
}

__global__ __launch_bounds__(256) void k_softmax(float* __restrict__ O, const float* __restrict__ bn2) {
    int w = (blockIdx.x * 256 + threadIdx.x) >> 6;
    if (w >= N_NODES) return;
    int lane = threadIdx.x & 63;
    float z = O[(size_t)w * NCLS + lane] * bn2[2 * NCLS + lane] + bn2[3 * NCLS + lane];
    float m = z;
#pragma unroll
    for (int o = 32; o > 0; o >>= 1) m = fmaxf(m, __shfl_xor(m, o));
    float e = __expf(z - m);
    float s = e;
#pragma unroll
    for (int o = 32; o > 0; o >>= 1) s += __shfl_xor(s, o);
    O[(size_t)w * NCLS + lane] = e / s;
}

// ---------- launch ----------
extern "C" void kernel_launch(void* const* d_in, const int* in_sizes, int n_in,
                              void* d_out, int out_size, void* d_ws, size_t ws_size,
                              hipStream_t stream) {
    const float* x = (const float*)d_in[0];
    const int* edge = (const int*)d_in[1];
    const int* srcp = edge;
    const int* dstp = edge + N_EDGES;
    const float* W1a = (const float*)d_in[9];
    const float* b1a = (const float*)d_in[10];
    const float* W1b = (const float*)d_in[11];
    const float* b1b = (const float*)d_in[12];
    const float* gamma1 = (const float*)d_in[13];
    const float* beta1 = (const float*)d_in[14];
    const float* W2a = (const float*)d_in[15];
    const float* b2a = (const float*)d_in[16];
    const float* W2b = (const float*)d_in[17];
    const float* b2b = (const float*)d_in[18];
    const float* gamma2 = (const float*)d_in[19];
    const float* beta2 = (const float*)d_in[20];
    float* out = (float*)d_out;

    char* ws = (char*)d_ws;
    size_t o = 0;
    auto alloc = [&](size_t bytes) -> char* {
        char* p = ws + o;
        o = (o + bytes + 255) & ~(size_t)255;
        return p;
    };
    int* off = (int*)alloc((N_NODES + 1) * sizeof(int));
    int* deg = (int*)alloc(N_NODES * sizeof(int));
    int* pos = (int*)alloc(N_NODES * sizeof(int));
    int* adj = (int*)alloc(N_EDGES * sizeof(int));
    float* bn1 = (float*)alloc(4 * HID * sizeof(float));
    float* bn2 = (float*)alloc(4 * NCLS * sizeof(float));
    unsigned short* Wp1 = (unsigned short*)alloc((size_t)IN_DIM * HID * sizeof(unsigned short));
    unsigned short* Wp2 = (unsigned short*)alloc((size_t)HID * HID * sizeof(unsigned short));
    unsigned short* Wp3 = (unsigned short*)alloc((size_t)HID * HID * sizeof(unsigned short));
    unsigned short* Wp4 = (unsigned short*)alloc((size_t)HID * NCLS * sizeof(unsigned short));
    unsigned short* A1 = (unsigned short*)alloc((size_t)N_NODES * IN_DIM * sizeof(unsigned short));
    unsigned short* B = (unsigned short*)alloc((size_t)N_NODES * HID * sizeof(unsigned short));
    unsigned short* C = (unsigned short*)alloc((size_t)N_NODES * HID * sizeof(unsigned short));

    hipMemsetAsync(deg, 0, N_NODES * sizeof(int), stream);
    hipMemsetAsync(bn1, 0, 2 * HID * sizeof(float), stream);
    hipMemsetAsync(bn2, 0, 2 * NCLS * sizeof(float), stream);

    int eb = (N_EDGES + 255) / 256;
    k_deg<<<eb, 256, 0, stream>>>(dstp, deg);
    k_scan<<<1, 1024, 0, stream>>>(deg, off, pos);
    k_fill<<<eb, 256, 0, stream>>>(srcp, dstp, pos, adj);

    // weight packing (tiny)
    k_pack<<<(IN_DIM * HID) / 256, 256, 0, stream>>>(W1a, Wp1, IN_DIM, HID);
    k_pack<<<(HID * HID) / 256, 256, 0, stream>>>(W1b, Wp2, HID, HID);
    k_pack<<<(HID * HID) / 256, 256, 0, stream>>>(W2a, Wp3, HID, HID);
    k_pack<<<(HID * NCLS) / 256, 256, 0, stream>>>(W2b, Wp4, HID, NCLS);

    int nwb = (N_NODES * 64 + 255) / 256;  // one wave per node
    k_agg1<<<nwb, 256, 0, stream>>>(x, off, adj, A1);

    dim3 gA((N_NODES + 63) / 64, HID / 256);  // 64-row blocks, 256-col blocks
    k_mgemm<IN_DIM, HID, 0, 2, 4, unsigned short><<<gA, 512, 0, stream>>>(A1, Wp1, b1a, B, N_NODES);
    k_mgemm<HID, HID, 1, 2, 4, unsigned short><<<gA, 512, 0, stream>>>(B, Wp2, b1b, C, N_NODES);

    k_bnstats_h<<<1024, 256, 0, stream>>>(C, bn1);
    k_bnprep<<<2, 256, 0, stream>>>(bn1, gamma1, beta1, HID, 1.0f / N_NODES);

    k_agg2<<<nwb, 256, 0, stream>>>(C, off, adj, bn1, B);

    k_mgemm<HID, HID, 0, 2, 4, unsigned short><<<gA, 512, 0, stream>>>(B, Wp3, b2a, C, N_NODES);
    dim3 gB((N_NODES + 255) / 256, 1);
    k_mgemm<HID, NCLS, 1, 8, 1, float><<<gB, 512, 0, stream>>>(C, Wp4, b2b, out, N_NODES);

    k_bnstats_o<<<1024, 256, 0, stream>>>(out, bn2);
    k_bnprep<<<1, 64, 0, stream>>>(bn2, gamma2, beta2, NCLS, 1.0f / N_NODES);
    k_softmax<<<nwb, 256, 0, stream>>>(out, bn2);
}

// Round 3
// 1309.493 us; speedup vs baseline: 2.0203x; 1.0025x over previous
//
#include <hip/hip_runtime.h>
#include <hip/hip_bf16.h>

#define N_NODES 100000
#define N_EDGES 1600000
#define IN_DIM 128
#define HID 512
#define NCLS 64

typedef __attribute__((ext_vector_type(8))) short bf16x8;
typedef __attribute__((ext_vector_type(4))) float f32x4;

// ---------- helpers ----------
__device__ inline float bf2f(unsigned short b) {
    unsigned int u = ((unsigned int)b) << 16;
    return __builtin_bit_cast(float, u);
}
__device__ inline unsigned short f2bf(float f) {
    unsigned int u = __builtin_bit_cast(unsigned int, f);
    unsigned int lsb = (u >> 16) & 1u;
    u += 0x7fffu + lsb;
    return (unsigned short)(u >> 16);
}
__device__ inline float selu_f(float x) {
    const float scale = 1.0507009873554805f;
    const float alpha = 1.6732632423543772f;
    return x > 0.f ? scale * x : scale * alpha * (__expf(x) - 1.f);
}
__device__ inline void stb(float* p, float v) { *p = v; }
__device__ inline void stb(unsigned short* p, float v) { *p = f2bf(v); }
__device__ inline void stb_nt(float* p, float v) { __builtin_nontemporal_store(v, p); }
__device__ inline void stb_nt(unsigned short* p, float v) { __builtin_nontemporal_store(f2bf(v), p); }

// ---------- x -> bf16 ----------
__global__ __launch_bounds__(256) void k_cast(const float* __restrict__ x,
                                              unsigned short* __restrict__ xb) {
    size_t g = (size_t)blockIdx.x * 256 + threadIdx.x;
    size_t total = (size_t)N_NODES * IN_DIM / 8;
    if (g >= total) return;
    const float4* p = (const float4*)(x + g * 8);
    float4 v0 = p[0], v1 = p[1];
    uint4 o;
    o.x = (unsigned)f2bf(v0.x) | ((unsigned)f2bf(v0.y) << 16);
    o.y = (unsigned)f2bf(v0.z) | ((unsigned)f2bf(v0.w) << 16);
    o.z = (unsigned)f2bf(v1.x) | ((unsigned)f2bf(v1.y) << 16);
    o.w = (unsigned)f2bf(v1.z) | ((unsigned)f2bf(v1.w) << 16);
    ((uint4*)xb)[g] = o;
}

// ---------- CSR build ----------
__global__ __launch_bounds__(256) void k_deg(const int* __restrict__ dst, int* __restrict__ deg) {
    int e = blockIdx.x * 256 + threadIdx.x;
    if (e < N_EDGES) atomicAdd(&deg[dst[e]], 1);
}

#define SCAN_NB 98  // ceil(100000/1024)

__global__ __launch_bounds__(256) void k_scan_part(const int* __restrict__ deg, int* __restrict__ part) {
    __shared__ int sd[256];
    int b = blockIdx.x, t = threadIdx.x;
    int i0 = b * 1024 + t * 4;
    int s = 0;
#pragma unroll
    for (int k = 0; k < 4; ++k) if (i0 + k < N_NODES) s += deg[i0 + k];
    sd[t] = s;
    __syncthreads();
    for (int o = 128; o > 0; o >>= 1) {
        if (t < o) sd[t] += sd[t + o];
        __syncthreads();
    }
    if (t == 0) part[b] = sd[0];
}

__global__ __launch_bounds__(128) void k_scan_mid(const int* __restrict__ part, int* __restrict__ base,
                                                  int* __restrict__ off) {
    __shared__ int sp[128];
    int t = threadIdx.x;
    int v = (t < SCAN_NB) ? part[t] : 0;
    sp[t] = v;
    __syncthreads();
    for (int o = 1; o < 128; o <<= 1) {
        int tv = (t >= o) ? sp[t - o] : 0;
        __syncthreads();
        sp[t] += tv;
        __syncthreads();
    }
    if (t < SCAN_NB) base[t] = sp[t] - v;
    if (t == SCAN_NB - 1) off[N_NODES] = sp[t];
}

__global__ __launch_bounds__(256) void k_scan_fin(const int* __restrict__ deg, const int* __restrict__ base,
                                                  int* __restrict__ off, int* __restrict__ pos) {
    __shared__ int sd[256];
    int b = blockIdx.x, t = threadIdx.x;
    int i0 = b * 1024 + t * 4;
    int v[4]; int s = 0;
#pragma unroll
    for (int k = 0; k < 4; ++k) { v[k] = (i0 + k < N_NODES) ? deg[i0 + k] : 0; s += v[k]; }
    sd[t] = s;
    __syncthreads();
    for (int o = 1; o < 256; o <<= 1) {
        int tv = (t >= o) ? sd[t - o] : 0;
        __syncthreads();
        sd[t] += tv;
        __syncthreads();
    }
    int excl = base[b] + sd[t] - s;
#pragma unroll
    for (int k = 0; k < 4; ++k) {
        if (i0 + k < N_NODES) { off[i0 + k] = excl; pos[i0 + k] = excl; excl += v[k]; }
    }
}

__global__ __launch_bounds__(256) void k_fill(const int* __restrict__ src, const int* __restrict__ dst,
                                              int* __restrict__ pos, int* __restrict__ adj) {
    int e = blockIdx.x * 256 + threadIdx.x;
    if (e < N_EDGES) {
        int p = atomicAdd(&pos[dst[e]], 1);
        adj[p] = src[e];
    }
}

// ---------- weight pack: W[K][NC] f32 -> fragment-ready bf16 ----------
// Wp[((nt*(K/32)+kt)*64 + lane)*8 + j] = bf16(W[kt*32 + (lane>>4)*8 + j][nt*16 + (lane&15)])
__global__ __launch_bounds__(256) void k_pack(const float* __restrict__ W,
                                              unsigned short* __restrict__ Wp, int K, int NC) {
    int idx = blockIdx.x * 256 + threadIdx.x;
    if (idx >= K * NC) return;
    int j = idx & 7;
    int l = (idx >> 3) & 63;
    int t = idx >> 9;
    int KT = K >> 5;
    int kt = t % KT;
    int nt = t / KT;
    int k = kt * 32 + (l >> 4) * 8 + j;
    int n = nt * 16 + (l & 15);
    Wp[idx] = f2bf(W[(size_t)k * NC + n]);
}

// ---------- fused gather + GEMM, layer 1 ----------
// For 64 nodes: agg rows (bf16 x, 128 feat) -> LDS (XOR swizzle) -> MFMA @W1a -> relu -> Out bf16
__global__ __launch_bounds__(512) void k_fuse1(const unsigned short* __restrict__ xb,
                                               const int* __restrict__ off, const int* __restrict__ adj,
                                               const unsigned short* __restrict__ Wp,
                                               const float* __restrict__ bias,
                                               unsigned short* __restrict__ Out) {
    __shared__ unsigned short sA[64 * IN_DIM];  // 16 KB
    const int tid = threadIdx.x;
    const int lane = tid & 63;
    const int w = tid >> 6;
    const int rowbase = blockIdx.x * 64;
    // gather: wave w owns local rows w*8 .. w*8+7
    for (int k = 0; k < 8; ++k) {
        int lr = w * 8 + k;
        int node = rowbase + lr;
        float s0 = 0.f, s1 = 0.f;
        if (node < N_NODES) {
            unsigned v = ((const unsigned*)(xb + (size_t)node * IN_DIM))[lane];
            s0 = bf2f((unsigned short)(v & 0xffff));
            s1 = bf2f((unsigned short)(v >> 16));
            int e0 = off[node], e1 = off[node + 1];
            int e = e0;
            for (; e + 4 <= e1; e += 4) {
                int j0 = adj[e], j1 = adj[e + 1], j2 = adj[e + 2], j3 = adj[e + 3];
                unsigned u0 = ((const unsigned*)(xb + (size_t)j0 * IN_DIM))[lane];
                unsigned u1 = ((const unsigned*)(xb + (size_t)j1 * IN_DIM))[lane];
                unsigned u2 = ((const unsigned*)(xb + (size_t)j2 * IN_DIM))[lane];
                unsigned u3 = ((const unsigned*)(xb + (size_t)j3 * IN_DIM))[lane];
                s0 += bf2f((unsigned short)(u0 & 0xffff)) + bf2f((unsigned short)(u1 & 0xffff)) +
                      bf2f((unsigned short)(u2 & 0xffff)) + bf2f((unsigned short)(u3 & 0xffff));
                s1 += bf2f((unsigned short)(u0 >> 16)) + bf2f((unsigned short)(u1 >> 16)) +
                      bf2f((unsigned short)(u2 >> 16)) + bf2f((unsigned short)(u3 >> 16));
            }
            for (; e < e1; ++e) {
                unsigned u = ((const unsigned*)(xb + (size_t)adj[e] * IN_DIM))[lane];
                s0 += bf2f((unsigned short)(u & 0xffff));
                s1 += bf2f((unsigned short)(u >> 16));
            }
        }
        unsigned o = (unsigned)f2bf(s0) | ((unsigned)f2bf(s1) << 16);
        int byte = (lane * 4) ^ ((lr & 7) << 4);
        *(unsigned*)((char*)sA + lr * (IN_DIM * 2) + byte) = o;
    }
    __syncthreads();
    // GEMM: 8 waves = 2M x 4N, per-wave 32 rows x 128 cols, K=128
    const int wm = w >> 2, wn = w & 3;
    const int l15 = lane & 15, lg = lane >> 4;
    const int colbase = wn * 128;
    const unsigned short* pw = Wp + (size_t)(colbase >> 4) * 4 * 512 + lane * 8;
    f32x4 acc[2][8];
#pragma unroll
    for (int i = 0; i < 2; ++i)
#pragma unroll
        for (int j = 0; j < 8; ++j) acc[i][j] = (f32x4)0.f;
    const int r0 = wm * 32 + l15, r1 = r0 + 16;
    const int sw0 = (r0 & 7) << 4, sw1 = (r1 & 7) << 4;
#pragma unroll
    for (int kt = 0; kt < 4; ++kt) {
        int cb = kt * 64 + lg * 16;
        bf16x8 a0 = *(const bf16x8*)((char*)sA + r0 * (IN_DIM * 2) + (cb ^ sw0));
        bf16x8 a1 = *(const bf16x8*)((char*)sA + r1 * (IN_DIM * 2) + (cb ^ sw1));
#pragma unroll
        for (int ni = 0; ni < 8; ++ni) {
            bf16x8 bv = *(const bf16x8*)(pw + (ni * 4 + kt) * 512);
            acc[0][ni] = __builtin_amdgcn_mfma_f32_16x16x32_bf16(a0, bv, acc[0][ni], 0, 0, 0);
            acc[1][ni] = __builtin_amdgcn_mfma_f32_16x16x32_bf16(a1, bv, acc[1][ni], 0, 0, 0);
        }
    }
#pragma unroll
    for (int ni = 0; ni < 8; ++ni) {
        int c = colbase + ni * 16 + l15;
        float bv = bias[c];
#pragma unroll
        for (int mi = 0; mi < 2; ++mi) {
#pragma unroll
            for (int r = 0; r < 4; ++r) {
                int row = rowbase + wm * 32 + mi * 16 + lg * 4 + r;
                if (row < N_NODES) {
                    float t = fmaxf(acc[mi][ni][r] + bv, 0.f);
                    stb(&Out[(size_t)row * HID + c], t);
                }
            }
        }
    }
}

// ---------- fused BN + gather + GEMM, layer 2 ----------
// For 64 nodes: agg rows of BN1(C) (512 feat) -> LDS (XOR swizzle) -> MFMA @W2a -> relu -> Out (NT)
__global__ __launch_bounds__(512) void k_fuse2(const unsigned short* __restrict__ h,
                                               const int* __restrict__ off, const int* __restrict__ adj,
                                               const float* __restrict__ bn,
                                               const unsigned short* __restrict__ Wp,
                                               const float* __restrict__ bias,
                                               unsigned short* __restrict__ Out) {
    __shared__ unsigned short sA[64 * HID];  // 64 KB
    const int tid = threadIdx.x;
    const int lane = tid & 63;
    const int w = tid >> 6;
    const int rowbase = blockIdx.x * 64;
    // per-lane BN constants (features lane*8 .. +7)
    float scl[8], shf[8];
#pragma unroll
    for (int j = 0; j < 8; ++j) {
        scl[j] = bn[2 * HID + lane * 8 + j];
        shf[j] = bn[3 * HID + lane * 8 + j];
    }
    for (int k = 0; k < 8; ++k) {
        int lr = w * 8 + k;
        int node = rowbase + lr;
        float s[8] = {0.f, 0.f, 0.f, 0.f, 0.f, 0.f, 0.f, 0.f};
        float dp1 = 0.f;
        if (node < N_NODES) {
            uint4 v = ((const uint4*)(h + (size_t)node * HID))[lane];
            s[0] = bf2f((unsigned short)(v.x & 0xffff)); s[1] = bf2f((unsigned short)(v.x >> 16));
            s[2] = bf2f((unsigned short)(v.y & 0xffff)); s[3] = bf2f((unsigned short)(v.y >> 16));
            s[4] = bf2f((unsigned short)(v.z & 0xffff)); s[5] = bf2f((unsigned short)(v.z >> 16));
            s[6] = bf2f((unsigned short)(v.w & 0xffff)); s[7] = bf2f((unsigned short)(v.w >> 16));
            int e0 = off[node], e1 = off[node + 1];
            dp1 = (float)(e1 - e0 + 1);
            int e = e0;
            for (; e + 4 <= e1; e += 4) {
                int j0 = adj[e], j1 = adj[e + 1], j2 = adj[e + 2], j3 = adj[e + 3];
                uint4 u0 = ((const uint4*)(h + (size_t)j0 * HID))[lane];
                uint4 u1 = ((const uint4*)(h + (size_t)j1 * HID))[lane];
                uint4 u2 = ((const uint4*)(h + (size_t)j2 * HID))[lane];
                uint4 u3 = ((const uint4*)(h + (size_t)j3 * HID))[lane];
                s[0] += bf2f((unsigned short)(u0.x & 0xffff)) + bf2f((unsigned short)(u1.x & 0xffff)) +
                        bf2f((unsigned short)(u2.x & 0xffff)) + bf2f((unsigned short)(u3.x & 0xffff));
                s[1] += bf2f((unsigned short)(u0.x >> 16)) + bf2f((unsigned short)(u1.x >> 16)) +
                        bf2f((unsigned short)(u2.x >> 16)) + bf2f((unsigned short)(u3.x >> 16));
                s[2] += bf2f((unsigned short)(u0.y & 0xffff)) + bf2f((unsigned short)(u1.y & 0xffff)) +
                        bf2f((unsigned short)(u2.y & 0xffff)) + bf2f((unsigned short)(u3.y & 0xffff));
                s[3] += bf2f((unsigned short)(u0.y >> 16)) + bf2f((unsigned short)(u1.y >> 16)) +
                        bf2f((unsigned short)(u2.y >> 16)) + bf2f((unsigned short)(u3.y >> 16));
                s[4] += bf2f((unsigned short)(u0.z & 0xffff)) + bf2f((unsigned short)(u1.z & 0xffff)) +
                        bf2f((unsigned short)(u2.z & 0xffff)) + bf2f((unsigned short)(u3.z & 0xffff));
                s[5] += bf2f((unsigned short)(u0.z >> 16)) + bf2f((unsigned short)(u1.z >> 16)) +
                        bf2f((unsigned short)(u2.z >> 16)) + bf2f((unsigned short)(u3.z >> 16));
                s[6] += bf2f((unsigned short)(u0.w & 0xffff)) + bf2f((unsigned short)(u1.w & 0xffff)) +
                        bf2f((unsigned short)(u2.w & 0xffff)) + bf2f((unsigned short)(u3.w & 0xffff));
                s[7] += bf2f((unsigned short)(u0.w >> 16)) + bf2f((unsigned short)(u1.w >> 16)) +
                        bf2f((unsigned short)(u2.w >> 16)) + bf2f((unsigned short)(u3.w >> 16));
            }
            for (; e < e1; ++e) {
                uint4 u = ((const uint4*)(h + (size_t)adj[e] * HID))[lane];
                s[0] += bf2f((unsigned short)(u.x & 0xffff)); s[1] += bf2f((unsigned short)(u.x >> 16));
                s[2] += bf2f((unsigned short)(u.y & 0xffff)); s[3] += bf2f((unsigned short)(u.y >> 16));
                s[4] += bf2f((unsigned short)(u.z & 0xffff)); s[5] += bf2f((unsigned short)(u.z >> 16));
                s[6] += bf2f((unsigned short)(u.w & 0xffff)); s[7] += bf2f((unsigned short)(u.w >> 16));
            }
        }
        float r[8];
#pragma unroll
        for (int j = 0; j < 8; ++j) r[j] = s[j] * scl[j] + dp1 * shf[j];
        uint4 o;
        o.x = (unsigned)f2bf(r[0]) | ((unsigned)f2bf(r[1]) << 16);
        o.y = (unsigned)f2bf(r[2]) | ((unsigned)f2bf(r[3]) << 16);
        o.z = (unsigned)f2bf(r[4]) | ((unsigned)f2bf(r[5]) << 16);
        o.w = (unsigned)f2bf(r[6]) | ((unsigned)f2bf(r[7]) << 16);
        int byte = (lane * 16) ^ ((lr & 7) << 4);
        *(uint4*)((char*)sA + lr * (HID * 2) + byte) = o;
    }
    __syncthreads();
    // GEMM: 8 waves = 2M x 4N, per-wave 32 rows x 128 cols, K=512
    const int wm = w >> 2, wn = w & 3;
    const int l15 = lane & 15, lg = lane >> 4;
    const int colbase = wn * 128;
    const unsigned short* pw = Wp + (size_t)(colbase >> 4) * 16 * 512 + lane * 8;
    f32x4 acc[2][8];
#pragma unroll
    for (int i = 0; i < 2; ++i)
#pragma unroll
        for (int j = 0; j < 8; ++j) acc[i][j] = (f32x4)0.f;
    const int r0 = wm * 32 + l15, r1 = r0 + 16;
    const int sw0 = (r0 & 7) << 4, sw1 = (r1 & 7) << 4;
#pragma unroll 2
    for (int kt = 0; kt < 16; ++kt) {
        int cb = kt * 64 + lg * 16;
        bf16x8 a0 = *(const bf16x8*)((char*)sA + r0 * (HID * 2) + (cb ^ sw0));
        bf16x8 a1 = *(const bf16x8*)((char*)sA + r1 * (HID * 2) + (cb ^ sw1));
#pragma unroll
        for (int ni = 0; ni < 8; ++ni) {
            bf16x8 bv = *(const bf16x8*)(pw + (ni * 16 + kt) * 512);
            acc[0][ni] = __builtin_amdgcn_mfma_f32_16x16x32_bf16(a0, bv, acc[0][ni], 0, 0, 0);
            acc[1][ni] = __builtin_amdgcn_mfma_f32_16x16x32_bf16(a1, bv, acc[1][ni], 0, 0, 0);
        }
    }
#pragma unroll
    for (int ni = 0; ni < 8; ++ni) {
        int c = colbase + ni * 16 + l15;
        float bv = bias[c];
#pragma unroll
        for (int mi = 0; mi < 2; ++mi) {
#pragma unroll
            for (int r = 0; r < 4; ++r) {
                int row = rowbase + wm * 32 + mi * 16 + lg * 4 + r;
                if (row < N_NODES) {
                    float t = fmaxf(acc[mi][ni][r] + bv, 0.f);
                    stb_nt(&Out[(size_t)row * HID + c], t);
                }
            }
        }
    }
}

// ---------- MFMA GEMM (no gather): Out[M,NC] = act(A @ W + bias) ----------
template <int K, int NC, int ACT, int WAVES_M, int WAVES_N, int NFRAG, int NT, typename TOUT>
__global__ __launch_bounds__(WAVES_M * WAVES_N * 64) void k_mgemm(
    const unsigned short* __restrict__ A, const unsigned short* __restrict__ Wp,
    const float* __restrict__ bias, TOUT* __restrict__ Out, int M) {
    const int tid = threadIdx.x;
    const int lane = tid & 63;
    const int w = tid >> 6;
    const int wm = w / WAVES_N;
    const int wn = w % WAVES_N;
    const int l15 = lane & 15;
    const int lg = lane >> 4;
    const int rowbase = blockIdx.x * (32 * WAVES_M) + wm * 32;
    const int colbase = blockIdx.y * (WAVES_N * 16 * NFRAG) + wn * 16 * NFRAG;
    int r0 = rowbase + l15; if (r0 > M - 1) r0 = M - 1;
    int r1 = rowbase + 16 + l15; if (r1 > M - 1) r1 = M - 1;
    const unsigned short* pa0 = A + (size_t)r0 * K + lg * 8;
    const unsigned short* pa1 = A + (size_t)r1 * K + lg * 8;
    const unsigned short* pw = Wp + (size_t)(colbase >> 4) * (K / 32) * 512 + lane * 8;

    f32x4 acc[2][NFRAG];
#pragma unroll
    for (int i = 0; i < 2; ++i)
#pragma unroll
        for (int j = 0; j < NFRAG; ++j) acc[i][j] = (f32x4)0.f;

#pragma unroll 2
    for (int kt = 0; kt < K / 32; ++kt) {
        bf16x8 a0 = *(const bf16x8*)(pa0 + kt * 32);
        bf16x8 a1 = *(const bf16x8*)(pa1 + kt * 32);
#pragma unroll
        for (int ni = 0; ni < NFRAG; ++ni) {
            bf16x8 bv = *(const bf16x8*)(pw + (ni * (K / 32) + kt) * 512);
            acc[0][ni] = __builtin_amdgcn_mfma_f32_16x16x32_bf16(a0, bv, acc[0][ni], 0, 0, 0);
            acc[1][ni] = __builtin_amdgcn_mfma_f32_16x16x32_bf16(a1, bv, acc[1][ni], 0, 0, 0);
        }
    }

#pragma unroll
    for (int ni = 0; ni < NFRAG; ++ni) {
        int c = colbase + ni * 16 + l15;
        float bv = bias[c];
#pragma unroll
        for (int mi = 0; mi < 2; ++mi) {
#pragma unroll
            for (int r = 0; r < 4; ++r) {
                int row = rowbase + mi * 16 + lg * 4 + r;
                if (row < M) {
                    float t = acc[mi][ni][r] + bv;
                    t = (ACT == 0) ? fmaxf(t, 0.f) : selu_f(t);
                    if (NT) stb_nt(&Out[(size_t)row * NC + c], t);
                    else stb(&Out[(size_t)row * NC + c], t);
                }
            }
        }
    }
}

// ---------- BatchNorm stats ----------
__global__ __launch_bounds__(256) void k_bnstats_h(const unsigned short* __restrict__ C,
                                                   float* __restrict__ sums) {
    int t = threadIdx.x;
    float s0 = 0, q0 = 0, s1 = 0, q1 = 0;
    for (int r = blockIdx.x; r < N_NODES; r += gridDim.x) {
        const unsigned short* row = C + (size_t)r * HID;
        float a = bf2f(row[t]);
        float c = bf2f(row[t + 256]);
        s0 += a; q0 += a * a;
        s1 += c; q1 += c * c;
    }
    atomicAdd(&sums[t], s0);
    atomicAdd(&sums[t + 256], s1);
    atomicAdd(&sums[HID + t], q0);
    atomicAdd(&sums[HID + t + 256], q1);
}

__global__ void k_bnprep(float* __restrict__ bn, const float* __restrict__ gamma,
                         const float* __restrict__ beta, int C, float invn) {
    int c = threadIdx.x + blockIdx.x * blockDim.x;
    if (c >= C) return;
    float mu = bn[c] * invn;
    float var = bn[C + c] * invn - mu * mu;
    float sc = gamma[c] * rsqrtf(var + 1e-5f);
    bn[2 * C + c] = sc;
    bn[3 * C + c] = beta[c] - mu * sc;
}

__global__ __launch_bounds__(256) void k_bnstats_o(const float* __restrict__ O,
                                                   float* __restrict__ bn2) {
    int t = threadIdx.x;
    int c = t & 63;
    int rr = t >> 6;
    float s = 0, q = 0;
    for (int r = blockIdx.x * 4 + rr; r < N_NODES; r += gridDim.x * 4) {
        float a = O[(size_t)r * NCLS + c];
        s += a; q += a * a;
    }
    atomicAdd(&bn2[c], s);
    atomicAdd(&bn2[NCLS + c], q);
}

__global__ __launch_bounds__(256) void k_softmax(float* __restrict__ O, const float* __restrict__ bn2) {
    int w = (blockIdx.x * 256 + threadIdx.x) >> 6;
    if (w >= N_NODES) return;
    int lane = threadIdx.x & 63;
    float z = O[(size_t)w * NCLS + lane] * bn2[2 * NCLS + lane] + bn2[3 * NCLS + lane];
    float m = z;
#pragma unroll
    for (int o = 32; o > 0; o >>= 1) m = fmaxf(m, __shfl_xor(m, o));
    float e = __expf(z - m);
    float s = e;
#pragma unroll
    for (int o = 32; o > 0; o >>= 1) s += __shfl_xor(s, o);
    O[(size_t)w * NCLS + lane] = e / s;
}

// ---------- launch ----------
extern "C" void kernel_launch(void* const* d_in, const int* in_sizes, int n_in,
                              void* d_out, int out_size, void* d_ws, size_t ws_size,
                              hipStream_t stream) {
    const float* x = (const float*)d_in[0];
    const int* edge = (const int*)d_in[1];
    const int* srcp = edge;
    const int* dstp = edge + N_EDGES;
    const float* W1a = (const float*)d_in[9];
    const float* b1a = (const float*)d_in[10];
    const float* W1b = (const float*)d_in[11];
    const float* b1b = (const float*)d_in[12];
    const float* gamma1 = (const float*)d_in[13];
    const float* beta1 = (const float*)d_in[14];
    const float* W2a = (const float*)d_in[15];
    const float* b2a = (const float*)d_in[16];
    const float* W2b = (const float*)d_in[17];
    const float* b2b = (const float*)d_in[18];
    const float* gamma2 = (const float*)d_in[19];
    const float* beta2 = (const float*)d_in[20];
    float* out = (float*)d_out;

    char* ws = (char*)d_ws;
    size_t o = 0;
    auto alloc = [&](size_t bytes) -> char* {
        char* p = ws + o;
        o = (o + bytes + 255) & ~(size_t)255;
        return p;
    };
    int* off = (int*)alloc((N_NODES + 1) * sizeof(int));
    int* deg = (int*)alloc(N_NODES * sizeof(int));
    int* pos = (int*)alloc(N_NODES * sizeof(int));
    int* adj = (int*)alloc(N_EDGES * sizeof(int));
    int* part = (int*)alloc(SCAN_NB * sizeof(int));
    int* base = (int*)alloc(SCAN_NB * sizeof(int));
    float* bn1 = (float*)alloc(4 * HID * sizeof(float));
    float* bn2 = (float*)alloc(4 * NCLS * sizeof(float));
    unsigned short* Wp1 = (unsigned short*)alloc((size_t)IN_DIM * HID * sizeof(unsigned short));
    unsigned short* Wp2 = (unsigned short*)alloc((size_t)HID * HID * sizeof(unsigned short));
    unsigned short* Wp3 = (unsigned short*)alloc((size_t)HID * HID * sizeof(unsigned short));
    unsigned short* Wp4 = (unsigned short*)alloc((size_t)HID * NCLS * sizeof(unsigned short));
    unsigned short* xb = (unsigned short*)alloc((size_t)N_NODES * IN_DIM * sizeof(unsigned short));
    unsigned short* B = (unsigned short*)alloc((size_t)N_NODES * HID * sizeof(unsigned short));
    unsigned short* C = (unsigned short*)alloc((size_t)N_NODES * HID * sizeof(unsigned short));

    hipMemsetAsync(deg, 0, N_NODES * sizeof(int), stream);
    hipMemsetAsync(bn1, 0, 2 * HID * sizeof(float), stream);
    hipMemsetAsync(bn2, 0, 2 * NCLS * sizeof(float), stream);

    int eb = (N_EDGES + 255) / 256;
    k_cast<<<(N_NODES * IN_DIM / 8 + 255) / 256, 256, 0, stream>>>(x, xb);
    k_deg<<<eb, 256, 0, stream>>>(dstp, deg);
    k_scan_part<<<SCAN_NB, 256, 0, stream>>>(deg, part);
    k_scan_mid<<<1, 128, 0, stream>>>(part, base, off);
    k_scan_fin<<<SCAN_NB, 256, 0, stream>>>(deg, base, off, pos);
    k_fill<<<eb, 256, 0, stream>>>(srcp, dstp, pos, adj);

    // weight packing (tiny)
    k_pack<<<(IN_DIM * HID) / 256, 256, 0, stream>>>(W1a, Wp1, IN_DIM, HID);
    k_pack<<<(HID * HID) / 256, 256, 0, stream>>>(W1b, Wp2, HID, HID);
    k_pack<<<(HID * HID) / 256, 256, 0, stream>>>(W2a, Wp3, HID, HID);
    k_pack<<<(HID * NCLS) / 256, 256, 0, stream>>>(W2b, Wp4, HID, NCLS);

    int nblk = (N_NODES + 63) / 64;
    // layer 1: fused agg(x) -> @W1a -> relu -> B
    k_fuse1<<<nblk, 512, 0, stream>>>(xb, off, adj, Wp1, b1a, B);
    // C = selu(B @ W1b + b1b)
    k_mgemm<HID, HID, 1, 2, 4, 8, 0, unsigned short><<<dim3(nblk, 1), 512, 0, stream>>>(B, Wp2, b1b, C, N_NODES);

    k_bnstats_h<<<1024, 256, 0, stream>>>(C, bn1);
    k_bnprep<<<2, 256, 0, stream>>>(bn1, gamma1, beta1, HID, 1.0f / N_NODES);

    // layer 2: fused BN1+agg(C) -> @W2a -> relu -> B (NT stores)
    k_fuse2<<<nblk, 512, 0, stream>>>(C, off, adj, bn1, Wp3, b2a, B);
    // out = selu(B @ W2b + b2b)
    k_mgemm<HID, NCLS, 1, 8, 1, 4, 0, float><<<dim3((N_NODES + 255) / 256, 1), 512, 0, stream>>>(B, Wp4, b2b, out, N_NODES);

    k_bnstats_o<<<1024, 256, 0, stream>>>(out, bn2);
    k_bnprep<<<1, 64, 0, stream>>>(bn2, gamma2, beta2, NCLS, 1.0f / N_NODES);
    k_softmax<<<(N_NODES * 64 + 255) / 256, 256, 0, stream>>>(out, bn2);
}

// Round 4
// 1250.986 us; speedup vs baseline: 2.1148x; 1.0468x over previous
//
#include <hip/hip_runtime.h>
#include <hip/hip_bf16.h>

#define N_NODES 100000
#define N_EDGES 1600000
#define IN_DIM 128
#define HID 512
#define NCLS 64

typedef __attribute__((ext_vector_type(8))) short bf16x8;
typedef __attribute__((ext_vector_type(4))) float f32x4;

// ---------- helpers ----------
__device__ inline float bf2f(unsigned short b) {
    unsigned int u = ((unsigned int)b) << 16;
    return __builtin_bit_cast(float, u);
}
__device__ inline unsigned short f2bf(float f) {
    unsigned int u = __builtin_bit_cast(unsigned int, f);
    unsigned int lsb = (u >> 16) & 1u;
    u += 0x7fffu + lsb;
    return (unsigned short)(u >> 16);
}
__device__ inline float selu_f(float x) {
    const float scale = 1.0507009873554805f;
    const float alpha = 1.6732632423543772f;
    return x > 0.f ? scale * x : scale * alpha * (__expf(x) - 1.f);
}
__device__ inline void stb(float* p, float v) { *p = v; }
__device__ inline void stb(unsigned short* p, float v) { *p = f2bf(v); }
__device__ inline void stb_nt(float* p, float v) { __builtin_nontemporal_store(v, p); }
__device__ inline void stb_nt(unsigned short* p, float v) { __builtin_nontemporal_store(f2bf(v), p); }

// ---------- x -> bf16 ----------
__global__ __launch_bounds__(256) void k_cast(const float* __restrict__ x,
                                              unsigned short* __restrict__ xb) {
    size_t g = (size_t)blockIdx.x * 256 + threadIdx.x;
    size_t total = (size_t)N_NODES * IN_DIM / 8;
    if (g >= total) return;
    const float4* p = (const float4*)(x + g * 8);
    float4 v0 = p[0], v1 = p[1];
    uint4 o;
    o.x = (unsigned)f2bf(v0.x) | ((unsigned)f2bf(v0.y) << 16);
    o.y = (unsigned)f2bf(v0.z) | ((unsigned)f2bf(v0.w) << 16);
    o.z = (unsigned)f2bf(v1.x) | ((unsigned)f2bf(v1.y) << 16);
    o.w = (unsigned)f2bf(v1.z) | ((unsigned)f2bf(v1.w) << 16);
    ((uint4*)xb)[g] = o;
}

// ---------- CSR build ----------
__global__ __launch_bounds__(256) void k_deg(const int* __restrict__ dst, int* __restrict__ deg) {
    int e = blockIdx.x * 256 + threadIdx.x;
    if (e < N_EDGES) atomicAdd(&deg[dst[e]], 1);
}

#define SCAN_NB 98  // ceil(100000/1024)

__global__ __launch_bounds__(256) void k_scan_part(const int* __restrict__ deg, int* __restrict__ part) {
    __shared__ int sd[256];
    int b = blockIdx.x, t = threadIdx.x;
    int i0 = b * 1024 + t * 4;
    int s = 0;
#pragma unroll
    for (int k = 0; k < 4; ++k) if (i0 + k < N_NODES) s += deg[i0 + k];
    sd[t] = s;
    __syncthreads();
    for (int o = 128; o > 0; o >>= 1) {
        if (t < o) sd[t] += sd[t + o];
        __syncthreads();
    }
    if (t == 0) part[b] = sd[0];
}

__global__ __launch_bounds__(128) void k_scan_mid(const int* __restrict__ part, int* __restrict__ base,
                                                  int* __restrict__ off) {
    __shared__ int sp[128];
    int t = threadIdx.x;
    int v = (t < SCAN_NB) ? part[t] : 0;
    sp[t] = v;
    __syncthreads();
    for (int o = 1; o < 128; o <<= 1) {
        int tv = (t >= o) ? sp[t - o] : 0;
        __syncthreads();
        sp[t] += tv;
        __syncthreads();
    }
    if (t < SCAN_NB) base[t] = sp[t] - v;
    if (t == SCAN_NB - 1) off[N_NODES] = sp[t];
}

__global__ __launch_bounds__(256) void k_scan_fin(const int* __restrict__ deg, const int* __restrict__ base,
                                                  int* __restrict__ off, int* __restrict__ pos) {
    __shared__ int sd[256];
    int b = blockIdx.x, t = threadIdx.x;
    int i0 = b * 1024 + t * 4;
    int v[4]; int s = 0;
#pragma unroll
    for (int k = 0; k < 4; ++k) { v[k] = (i0 + k < N_NODES) ? deg[i0 + k] : 0; s += v[k]; }
    sd[t] = s;
    __syncthreads();
    for (int o = 1; o < 256; o <<= 1) {
        int tv = (t >= o) ? sd[t - o] : 0;
        __syncthreads();
        sd[t] += tv;
        __syncthreads();
    }
    int excl = base[b] + sd[t] - s;
#pragma unroll
    for (int k = 0; k < 4; ++k) {
        if (i0 + k < N_NODES) { off[i0 + k] = excl; pos[i0 + k] = excl; excl += v[k]; }
    }
}

__global__ __launch_bounds__(256) void k_fill(const int* __restrict__ src, const int* __restrict__ dst,
                                              int* __restrict__ pos, int* __restrict__ adj) {
    int e = blockIdx.x * 256 + threadIdx.x;
    if (e < N_EDGES) {
        int p = atomicAdd(&pos[dst[e]], 1);
        adj[p] = src[e];
    }
}

// ---------- weight pack: W[K][NC] f32 -> fragment-ready bf16 ----------
__global__ __launch_bounds__(256) void k_pack(const float* __restrict__ W,
                                              unsigned short* __restrict__ Wp, int K, int NC) {
    int idx = blockIdx.x * 256 + threadIdx.x;
    if (idx >= K * NC) return;
    int j = idx & 7;
    int l = (idx >> 3) & 63;
    int t = idx >> 9;
    int KT = K >> 5;
    int kt = t % KT;
    int nt = t / KT;
    int k = kt * 32 + (l >> 4) * 8 + j;
    int n = nt * 16 + (l & 15);
    Wp[idx] = f2bf(W[(size_t)k * NC + n]);
}

// ---------- aggregation layer 1: A1[w] = x[w] + sum_{j in N(w)} x[j]  (bf16, 128 feat) ----------
__global__ __launch_bounds__(256) void k_agg1(const unsigned short* __restrict__ xb,
                                              const int* __restrict__ off, const int* __restrict__ adj,
                                              unsigned short* __restrict__ A1) {
    int w = (blockIdx.x * 256 + threadIdx.x) >> 6;
    if (w >= N_NODES) return;
    int lane = threadIdx.x & 63;
    unsigned v = ((const unsigned*)(xb + (size_t)w * IN_DIM))[lane];
    float s0 = bf2f((unsigned short)(v & 0xffff));
    float s1 = bf2f((unsigned short)(v >> 16));
    int e0 = off[w], e1 = off[w + 1];
    int e = e0;
    for (; e + 4 <= e1; e += 4) {
        int j0 = adj[e], j1 = adj[e + 1], j2 = adj[e + 2], j3 = adj[e + 3];
        unsigned u0 = ((const unsigned*)(xb + (size_t)j0 * IN_DIM))[lane];
        unsigned u1 = ((const unsigned*)(xb + (size_t)j1 * IN_DIM))[lane];
        unsigned u2 = ((const unsigned*)(xb + (size_t)j2 * IN_DIM))[lane];
        unsigned u3 = ((const unsigned*)(xb + (size_t)j3 * IN_DIM))[lane];
        s0 += bf2f((unsigned short)(u0 & 0xffff)) + bf2f((unsigned short)(u1 & 0xffff)) +
              bf2f((unsigned short)(u2 & 0xffff)) + bf2f((unsigned short)(u3 & 0xffff));
        s1 += bf2f((unsigned short)(u0 >> 16)) + bf2f((unsigned short)(u1 >> 16)) +
              bf2f((unsigned short)(u2 >> 16)) + bf2f((unsigned short)(u3 >> 16));
    }
    for (; e < e1; ++e) {
        unsigned u = ((const unsigned*)(xb + (size_t)adj[e] * IN_DIM))[lane];
        s0 += bf2f((unsigned short)(u & 0xffff));
        s1 += bf2f((unsigned short)(u >> 16));
    }
    ((unsigned*)(A1 + (size_t)w * IN_DIM))[lane] = (unsigned)f2bf(s0) | ((unsigned)f2bf(s1) << 16);
}

// ---------- aggregation layer 2, feature-sliced, BN1 fused ----------
// slice = blockIdx.y (0/1), covers features [slice*256, slice*256+256).
// out = scale * (sum_{j in {w} u N(w)} h_j) + (deg+1)*shift   (NT store)
__global__ __launch_bounds__(256) void k_aggbn2(const unsigned short* __restrict__ h,
                                                const int* __restrict__ off, const int* __restrict__ adj,
                                                const float* __restrict__ bn,
                                                unsigned short* __restrict__ outb) {
    int w = (blockIdx.x * 256 + threadIdx.x) >> 6;
    if (w >= N_NODES) return;
    int lane = threadIdx.x & 63;
    int fb = blockIdx.y * 256 + lane * 4;  // 4 features per lane
    const unsigned short* hp = h + fb;
    float scl[4], shf[4];
#pragma unroll
    for (int k = 0; k < 4; ++k) {
        scl[k] = bn[2 * HID + fb + k];
        shf[k] = bn[3 * HID + fb + k];
    }
    uint2 v = *(const uint2*)(hp + (size_t)w * HID);
    float s0 = bf2f((unsigned short)(v.x & 0xffff));
    float s1 = bf2f((unsigned short)(v.x >> 16));
    float s2 = bf2f((unsigned short)(v.y & 0xffff));
    float s3 = bf2f((unsigned short)(v.y >> 16));
    int e0 = off[w], e1 = off[w + 1];
    int e = e0;
    for (; e + 4 <= e1; e += 4) {
        int j0 = adj[e], j1 = adj[e + 1], j2 = adj[e + 2], j3 = adj[e + 3];
        uint2 u0 = *(const uint2*)(hp + (size_t)j0 * HID);
        uint2 u1 = *(const uint2*)(hp + (size_t)j1 * HID);
        uint2 u2 = *(const uint2*)(hp + (size_t)j2 * HID);
        uint2 u3 = *(const uint2*)(hp + (size_t)j3 * HID);
        s0 += bf2f((unsigned short)(u0.x & 0xffff)) + bf2f((unsigned short)(u1.x & 0xffff)) +
              bf2f((unsigned short)(u2.x & 0xffff)) + bf2f((unsigned short)(u3.x & 0xffff));
        s1 += bf2f((unsigned short)(u0.x >> 16)) + bf2f((unsigned short)(u1.x >> 16)) +
              bf2f((unsigned short)(u2.x >> 16)) + bf2f((unsigned short)(u3.x >> 16));
        s2 += bf2f((unsigned short)(u0.y & 0xffff)) + bf2f((unsigned short)(u1.y & 0xffff)) +
              bf2f((unsigned short)(u2.y & 0xffff)) + bf2f((unsigned short)(u3.y & 0xffff));
        s3 += bf2f((unsigned short)(u0.y >> 16)) + bf2f((unsigned short)(u1.y >> 16)) +
              bf2f((unsigned short)(u2.y >> 16)) + bf2f((unsigned short)(u3.y >> 16));
    }
    for (; e < e1; ++e) {
        uint2 u = *(const uint2*)(hp + (size_t)adj[e] * HID);
        s0 += bf2f((unsigned short)(u.x & 0xffff));
        s1 += bf2f((unsigned short)(u.x >> 16));
        s2 += bf2f((unsigned short)(u.y & 0xffff));
        s3 += bf2f((unsigned short)(u.y >> 16));
    }
    float dp1 = (float)(e1 - e0 + 1);
    float r0 = s0 * scl[0] + dp1 * shf[0];
    float r1 = s1 * scl[1] + dp1 * shf[1];
    float r2 = s2 * scl[2] + dp1 * shf[2];
    float r3 = s3 * scl[3] + dp1 * shf[3];
    unsigned long long o =
        (unsigned long long)((unsigned)f2bf(r0) | ((unsigned)f2bf(r1) << 16)) |
        ((unsigned long long)((unsigned)f2bf(r2) | ((unsigned)f2bf(r3) << 16)) << 32);
    __builtin_nontemporal_store(o, (unsigned long long*)(outb + (size_t)w * HID + fb));
}

// ---------- MFMA GEMM: Out[M,NC] = act(A @ W + bias) ----------
template <int K, int NC, int ACT, int WAVES_M, int WAVES_N, int NFRAG, typename TOUT>
__global__ __launch_bounds__(WAVES_M * WAVES_N * 64) void k_mgemm(
    const unsigned short* __restrict__ A, const unsigned short* __restrict__ Wp,
    const float* __restrict__ bias, TOUT* __restrict__ Out, int M) {
    const int tid = threadIdx.x;
    const int lane = tid & 63;
    const int w = tid >> 6;
    const int wm = w / WAVES_N;
    const int wn = w % WAVES_N;
    const int l15 = lane & 15;
    const int lg = lane >> 4;
    const int rowbase = blockIdx.x * (32 * WAVES_M) + wm * 32;
    const int colbase = blockIdx.y * (WAVES_N * 16 * NFRAG) + wn * 16 * NFRAG;
    int r0 = rowbase + l15; if (r0 > M - 1) r0 = M - 1;
    int r1 = rowbase + 16 + l15; if (r1 > M - 1) r1 = M - 1;
    const unsigned short* pa0 = A + (size_t)r0 * K + lg * 8;
    const unsigned short* pa1 = A + (size_t)r1 * K + lg * 8;
    const unsigned short* pw = Wp + (size_t)(colbase >> 4) * (K / 32) * 512 + lane * 8;

    f32x4 acc[2][NFRAG];
#pragma unroll
    for (int i = 0; i < 2; ++i)
#pragma unroll
        for (int j = 0; j < NFRAG; ++j) acc[i][j] = (f32x4)0.f;

#pragma unroll 2
    for (int kt = 0; kt < K / 32; ++kt) {
        bf16x8 a0 = *(const bf16x8*)(pa0 + kt * 32);
        bf16x8 a1 = *(const bf16x8*)(pa1 + kt * 32);
#pragma unroll
        for (int ni = 0; ni < NFRAG; ++ni) {
            bf16x8 bv = *(const bf16x8*)(pw + (ni * (K / 32) + kt) * 512);
            acc[0][ni] = __builtin_amdgcn_mfma_f32_16x16x32_bf16(a0, bv, acc[0][ni], 0, 0, 0);
            acc[1][ni] = __builtin_amdgcn_mfma_f32_16x16x32_bf16(a1, bv, acc[1][ni], 0, 0, 0);
        }
    }

#pragma unroll
    for (int ni = 0; ni < NFRAG; ++ni) {
        int c = colbase + ni * 16 + l15;
        float bv = bias[c];
#pragma unroll
        for (int mi = 0; mi < 2; ++mi) {
#pragma unroll
            for (int r = 0; r < 4; ++r) {
                int row = rowbase + mi * 16 + lg * 4 + r;
                if (row < M) {
                    float t = acc[mi][ni][r] + bv;
                    t = (ACT == 0) ? fmaxf(t, 0.f) : selu_f(t);
                    stb(&Out[(size_t)row * NC + c], t);
                }
            }
        }
    }
}

// ---------- BatchNorm stats (vectorized uint loads) ----------
__global__ __launch_bounds__(256) void k_bnstats_h(const unsigned short* __restrict__ C,
                                                   float* __restrict__ sums) {
    int t = threadIdx.x;  // covers features 2t, 2t+1
    float s0 = 0, q0 = 0, s1 = 0, q1 = 0;
    for (int r = blockIdx.x; r < N_NODES; r += gridDim.x) {
        unsigned v = ((const unsigned*)(C + (size_t)r * HID))[t];
        float a = bf2f((unsigned short)(v & 0xffff));
        float b = bf2f((unsigned short)(v >> 16));
        s0 += a; q0 += a * a;
        s1 += b; q1 += b * b;
    }
    atomicAdd(&sums[2 * t], s0);
    atomicAdd(&sums[2 * t + 1], s1);
    atomicAdd(&sums[HID + 2 * t], q0);
    atomicAdd(&sums[HID + 2 * t + 1], q1);
}

__global__ void k_bnprep(float* __restrict__ bn, const float* __restrict__ gamma,
                         const float* __restrict__ beta, int C, float invn) {
    int c = threadIdx.x + blockIdx.x * blockDim.x;
    if (c >= C) return;
    float mu = bn[c] * invn;
    float var = bn[C + c] * invn - mu * mu;
    float sc = gamma[c] * rsqrtf(var + 1e-5f);
    bn[2 * C + c] = sc;
    bn[3 * C + c] = beta[c] - mu * sc;
}

__global__ __launch_bounds__(256) void k_bnstats_o(const float* __restrict__ O,
                                                   float* __restrict__ bn2) {
    int t = threadIdx.x;
    int c = t & 63;
    int rr = t >> 6;
    float s = 0, q = 0;
    for (int r = blockIdx.x * 4 + rr; r < N_NODES; r += gridDim.x * 4) {
        float a = O[(size_t)r * NCLS + c];
        s += a; q += a * a;
    }
    atomicAdd(&bn2[c], s);
    atomicAdd(&bn2[NCLS + c], q);
}

__global__ __launch_bounds__(256) void k_softmax(float* __restrict__ O, const float* __restrict__ bn2) {
    int w = (blockIdx.x * 256 + threadIdx.x) >> 6;
    if (w >= N_NODES) return;
    int lane = threadIdx.x & 63;
    float z = O[(size_t)w * NCLS + lane] * bn2[2 * NCLS + lane] + bn2[3 * NCLS + lane];
    float m = z;
#pragma unroll
    for (int o = 32; o > 0; o >>= 1) m = fmaxf(m, __shfl_xor(m, o));
    float e = __expf(z - m);
    float s = e;
#pragma unroll
    for (int o = 32; o > 0; o >>= 1) s += __shfl_xor(s, o);
    O[(size_t)w * NCLS + lane] = e / s;
}

// ---------- launch ----------
extern "C" void kernel_launch(void* const* d_in, const int* in_sizes, int n_in,
                              void* d_out, int out_size, void* d_ws, size_t ws_size,
                              hipStream_t stream) {
    const float* x = (const float*)d_in[0];
    const int* edge = (const int*)d_in[1];
    const int* srcp = edge;
    const int* dstp = edge + N_EDGES;
    const float* W1a = (const float*)d_in[9];
    const float* b1a = (const float*)d_in[10];
    const float* W1b = (const float*)d_in[11];
    const float* b1b = (const float*)d_in[12];
    const float* gamma1 = (const float*)d_in[13];
    const float* beta1 = (const float*)d_in[14];
    const float* W2a = (const float*)d_in[15];
    const float* b2a = (const float*)d_in[16];
    const float* W2b = (const float*)d_in[17];
    const float* b2b = (const float*)d_in[18];
    const float* gamma2 = (const float*)d_in[19];
    const float* beta2 = (const float*)d_in[20];
    float* out = (float*)d_out;

    char* ws = (char*)d_ws;
    size_t o = 0;
    auto alloc = [&](size_t bytes) -> char* {
        char* p = ws + o;
        o = (o + bytes + 255) & ~(size_t)255;
        return p;
    };
    int* off = (int*)alloc((N_NODES + 1) * sizeof(int));
    int* deg = (int*)alloc(N_NODES * sizeof(int));
    int* pos = (int*)alloc(N_NODES * sizeof(int));
    int* adj = (int*)alloc(N_EDGES * sizeof(int));
    int* part = (int*)alloc(SCAN_NB * sizeof(int));
    int* base = (int*)alloc(SCAN_NB * sizeof(int));
    float* bn1 = (float*)alloc(4 * HID * sizeof(float));
    float* bn2 = (float*)alloc(4 * NCLS * sizeof(float));
    unsigned short* Wp1 = (unsigned short*)alloc((size_t)IN_DIM * HID * sizeof(unsigned short));
    unsigned short* Wp2 = (unsigned short*)alloc((size_t)HID * HID * sizeof(unsigned short));
    unsigned short* Wp3 = (unsigned short*)alloc((size_t)HID * HID * sizeof(unsigned short));
    unsigned short* Wp4 = (unsigned short*)alloc((size_t)HID * NCLS * sizeof(unsigned short));
    unsigned short* xb = (unsigned short*)alloc((size_t)N_NODES * IN_DIM * sizeof(unsigned short));
    unsigned short* A1 = (unsigned short*)alloc((size_t)N_NODES * IN_DIM * sizeof(unsigned short));
    unsigned short* B = (unsigned short*)alloc((size_t)N_NODES * HID * sizeof(unsigned short));
    unsigned short* C = (unsigned short*)alloc((size_t)N_NODES * HID * sizeof(unsigned short));

    hipMemsetAsync(deg, 0, N_NODES * sizeof(int), stream);
    hipMemsetAsync(bn1, 0, 2 * HID * sizeof(float), stream);
    hipMemsetAsync(bn2, 0, 2 * NCLS * sizeof(float), stream);

    int eb = (N_EDGES + 255) / 256;
    k_cast<<<(N_NODES * IN_DIM / 8 + 255) / 256, 256, 0, stream>>>(x, xb);
    k_deg<<<eb, 256, 0, stream>>>(dstp, deg);
    k_scan_part<<<SCAN_NB, 256, 0, stream>>>(deg, part);
    k_scan_mid<<<1, 128, 0, stream>>>(part, base, off);
    k_scan_fin<<<SCAN_NB, 256, 0, stream>>>(deg, base, off, pos);
    k_fill<<<eb, 256, 0, stream>>>(srcp, dstp, pos, adj);

    // weight packing (tiny)
    k_pack<<<(IN_DIM * HID) / 256, 256, 0, stream>>>(W1a, Wp1, IN_DIM, HID);
    k_pack<<<(HID * HID) / 256, 256, 0, stream>>>(W1b, Wp2, HID, HID);
    k_pack<<<(HID * HID) / 256, 256, 0, stream>>>(W2a, Wp3, HID, HID);
    k_pack<<<(HID * NCLS) / 256, 256, 0, stream>>>(W2b, Wp4, HID, NCLS);

    int nwb = (N_NODES * 64 + 255) / 256;  // one wave per node
    int nblk = (N_NODES + 63) / 64;

    // layer 1
    k_agg1<<<nwb, 256, 0, stream>>>(xb, off, adj, A1);
    k_mgemm<IN_DIM, HID, 0, 2, 4, 8, unsigned short><<<dim3(nblk, 1), 512, 0, stream>>>(A1, Wp1, b1a, B, N_NODES);
    k_mgemm<HID, HID, 1, 2, 4, 8, unsigned short><<<dim3(nblk, 1), 512, 0, stream>>>(B, Wp2, b1b, C, N_NODES);

    k_bnstats_h<<<1024, 256, 0, stream>>>(C, bn1);
    k_bnprep<<<2, 256, 0, stream>>>(bn1, gamma1, beta1, HID, 1.0f / N_NODES);

    // layer 2: feature-sliced gather with fused BN1
    k_aggbn2<<<dim3(nwb, 2), 256, 0, stream>>>(C, off, adj, bn1, B);

    k_mgemm<HID, HID, 0, 2, 4, 8, unsigned short><<<dim3(nblk, 1), 512, 0, stream>>>(B, Wp3, b2a, C, N_NODES);
    k_mgemm<HID, NCLS, 1, 8, 1, 4, float><<<dim3((N_NODES + 255) / 256, 1), 512, 0, stream>>>(C, Wp4, b2b, out, N_NODES);

    k_bnstats_o<<<1024, 256, 0, stream>>>(out, bn2);
    k_bnprep<<<1, 64, 0, stream>>>(bn2, gamma2, beta2, NCLS, 1.0f / N_NODES);
    k_softmax<<<nwb, 256, 0, stream>>>(out, bn2);
}

// Round 5
// 1017.553 us; speedup vs baseline: 2.5999x; 1.2294x over previous
//
#include <hip/hip_runtime.h>
#include <hip/hip_bf16.h>

#define N_NODES 100000
#define N_EDGES 1600000
#define IN_DIM 128
#define HID 512
#define NCLS 64

typedef __attribute__((ext_vector_type(8))) short bf16x8;
typedef __attribute__((ext_vector_type(4))) float f32x4;

// ---------- helpers ----------
__device__ inline float bf2f(unsigned short b) {
    unsigned int u = ((unsigned int)b) << 16;
    return __builtin_bit_cast(float, u);
}
__device__ inline unsigned short f2bf(float f) {
    unsigned int u = __builtin_bit_cast(unsigned int, f);
    unsigned int lsb = (u >> 16) & 1u;
    u += 0x7fffu + lsb;
    return (unsigned short)(u >> 16);
}
__device__ inline float selu_f(float x) {
    const float scale = 1.0507009873554805f;
    const float alpha = 1.6732632423543772f;
    return x > 0.f ? scale * x : scale * alpha * (__expf(x) - 1.f);
}
__device__ inline void stb(float* p, float v) { *p = v; }
__device__ inline void stb(unsigned short* p, float v) { *p = f2bf(v); }

// global -> LDS async 16B copy. dst must be wave-uniform; HW writes lane i at dst + i*16.
__device__ inline void gl_lds16(const void* g, void* l) {
    __builtin_amdgcn_global_load_lds((const __attribute__((address_space(1))) void*)g,
                                     (__attribute__((address_space(3))) void*)l, 16, 0, 0);
}

// ---------- x -> bf16 ----------
__global__ __launch_bounds__(256) void k_cast(const float* __restrict__ x,
                                              unsigned short* __restrict__ xb) {
    size_t g = (size_t)blockIdx.x * 256 + threadIdx.x;
    size_t total = (size_t)N_NODES * IN_DIM / 8;
    if (g >= total) return;
    const float4* p = (const float4*)(x + g * 8);
    float4 v0 = p[0], v1 = p[1];
    uint4 o;
    o.x = (unsigned)f2bf(v0.x) | ((unsigned)f2bf(v0.y) << 16);
    o.y = (unsigned)f2bf(v0.z) | ((unsigned)f2bf(v0.w) << 16);
    o.z = (unsigned)f2bf(v1.x) | ((unsigned)f2bf(v1.y) << 16);
    o.w = (unsigned)f2bf(v1.z) | ((unsigned)f2bf(v1.w) << 16);
    ((uint4*)xb)[g] = o;
}

// ---------- CSR build ----------
__global__ __launch_bounds__(256) void k_deg(const int* __restrict__ dst, int* __restrict__ deg) {
    int e = blockIdx.x * 256 + threadIdx.x;
    if (e < N_EDGES) atomicAdd(&deg[dst[e]], 1);
}

#define SCAN_NB 98  // ceil(100000/1024)

__global__ __launch_bounds__(256) void k_scan_part(const int* __restrict__ deg, int* __restrict__ part) {
    __shared__ int sd[256];
    int b = blockIdx.x, t = threadIdx.x;
    int i0 = b * 1024 + t * 4;
    int s = 0;
#pragma unroll
    for (int k = 0; k < 4; ++k) if (i0 + k < N_NODES) s += deg[i0 + k];
    sd[t] = s;
    __syncthreads();
    for (int o = 128; o > 0; o >>= 1) {
        if (t < o) sd[t] += sd[t + o];
        __syncthreads();
    }
    if (t == 0) part[b] = sd[0];
}

__global__ __launch_bounds__(128) void k_scan_mid(const int* __restrict__ part, int* __restrict__ base,
                                                  int* __restrict__ off) {
    __shared__ int sp[128];
    int t = threadIdx.x;
    int v = (t < SCAN_NB) ? part[t] : 0;
    sp[t] = v;
    __syncthreads();
    for (int o = 1; o < 128; o <<= 1) {
        int tv = (t >= o) ? sp[t - o] : 0;
        __syncthreads();
        sp[t] += tv;
        __syncthreads();
    }
    if (t < SCAN_NB) base[t] = sp[t] - v;
    if (t == SCAN_NB - 1) off[N_NODES] = sp[t];
}

__global__ __launch_bounds__(256) void k_scan_fin(const int* __restrict__ deg, const int* __restrict__ base,
                                                  int* __restrict__ off, int* __restrict__ pos) {
    __shared__ int sd[256];
    int b = blockIdx.x, t = threadIdx.x;
    int i0 = b * 1024 + t * 4;
    int v[4]; int s = 0;
#pragma unroll
    for (int k = 0; k < 4; ++k) { v[k] = (i0 + k < N_NODES) ? deg[i0 + k] : 0; s += v[k]; }
    sd[t] = s;
    __syncthreads();
    for (int o = 1; o < 256; o <<= 1) {
        int tv = (t >= o) ? sd[t - o] : 0;
        __syncthreads();
        sd[t] += tv;
        __syncthreads();
    }
    int excl = base[b] + sd[t] - s;
#pragma unroll
    for (int k = 0; k < 4; ++k) {
        if (i0 + k < N_NODES) { off[i0 + k] = excl; pos[i0 + k] = excl; excl += v[k]; }
    }
}

__global__ __launch_bounds__(256) void k_fill(const int* __restrict__ src, const int* __restrict__ dst,
                                              int* __restrict__ pos, int* __restrict__ adj) {
    int e = blockIdx.x * 256 + threadIdx.x;
    if (e < N_EDGES) {
        int p = atomicAdd(&pos[dst[e]], 1);
        adj[p] = src[e];
    }
}

// ---------- weight packs ----------
// fragment-pack (for the small final GEMM)
__global__ __launch_bounds__(256) void k_pack(const float* __restrict__ W,
                                              unsigned short* __restrict__ Wp, int K, int NC) {
    int idx = blockIdx.x * 256 + threadIdx.x;
    if (idx >= K * NC) return;
    int j = idx & 7;
    int l = (idx >> 3) & 63;
    int t = idx >> 9;
    int KT = K >> 5;
    int kt = t % KT;
    int nt = t / KT;
    int k = kt * 32 + (l >> 4) * 8 + j;
    int n = nt * 16 + (l & 15);
    Wp[idx] = f2bf(W[(size_t)k * NC + n]);
}

// transpose-pack: WT[n*K + k] = bf16(W[k*NC + n])
__global__ __launch_bounds__(256) void k_packT(const float* __restrict__ W,
                                               unsigned short* __restrict__ WT, int K, int NC) {
    int idx = blockIdx.x * 256 + threadIdx.x;
    if (idx >= K * NC) return;
    int k = idx & (K - 1);
    int n = idx / K;
    WT[idx] = f2bf(W[(size_t)k * NC + n]);
}

// ---------- aggregation layer 1 ----------
__global__ __launch_bounds__(256) void k_agg1(const unsigned short* __restrict__ xb,
                                              const int* __restrict__ off, const int* __restrict__ adj,
                                              unsigned short* __restrict__ A1) {
    int w = (blockIdx.x * 256 + threadIdx.x) >> 6;
    if (w >= N_NODES) return;
    int lane = threadIdx.x & 63;
    unsigned v = ((const unsigned*)(xb + (size_t)w * IN_DIM))[lane];
    float s0 = bf2f((unsigned short)(v & 0xffff));
    float s1 = bf2f((unsigned short)(v >> 16));
    int e0 = off[w], e1 = off[w + 1];
    int e = e0;
    for (; e + 4 <= e1; e += 4) {
        int j0 = adj[e], j1 = adj[e + 1], j2 = adj[e + 2], j3 = adj[e + 3];
        unsigned u0 = ((const unsigned*)(xb + (size_t)j0 * IN_DIM))[lane];
        unsigned u1 = ((const unsigned*)(xb + (size_t)j1 * IN_DIM))[lane];
        unsigned u2 = ((const unsigned*)(xb + (size_t)j2 * IN_DIM))[lane];
        unsigned u3 = ((const unsigned*)(xb + (size_t)j3 * IN_DIM))[lane];
        s0 += bf2f((unsigned short)(u0 & 0xffff)) + bf2f((unsigned short)(u1 & 0xffff)) +
              bf2f((unsigned short)(u2 & 0xffff)) + bf2f((unsigned short)(u3 & 0xffff));
        s1 += bf2f((unsigned short)(u0 >> 16)) + bf2f((unsigned short)(u1 >> 16)) +
              bf2f((unsigned short)(u2 >> 16)) + bf2f((unsigned short)(u3 >> 16));
    }
    for (; e < e1; ++e) {
        unsigned u = ((const unsigned*)(xb + (size_t)adj[e] * IN_DIM))[lane];
        s0 += bf2f((unsigned short)(u & 0xffff));
        s1 += bf2f((unsigned short)(u >> 16));
    }
    ((unsigned*)(A1 + (size_t)w * IN_DIM))[lane] = (unsigned)f2bf(s0) | ((unsigned)f2bf(s1) << 16);
}

// ---------- aggregation layer 2, feature-sliced, BN1 fused ----------
__global__ __launch_bounds__(256) void k_aggbn2(const unsigned short* __restrict__ h,
                                                const int* __restrict__ off, const int* __restrict__ adj,
                                                const float* __restrict__ bn,
                                                unsigned short* __restrict__ outb) {
    int w = (blockIdx.x * 256 + threadIdx.x) >> 6;
    if (w >= N_NODES) return;
    int lane = threadIdx.x & 63;
    int fb = blockIdx.y * 256 + lane * 4;
    const unsigned short* hp = h + fb;
    float scl[4], shf[4];
#pragma unroll
    for (int k = 0; k < 4; ++k) {
        scl[k] = bn[2 * HID + fb + k];
        shf[k] = bn[3 * HID + fb + k];
    }
    uint2 v = *(const uint2*)(hp + (size_t)w * HID);
    float s0 = bf2f((unsigned short)(v.x & 0xffff));
    float s1 = bf2f((unsigned short)(v.x >> 16));
    float s2 = bf2f((unsigned short)(v.y & 0xffff));
    float s3 = bf2f((unsigned short)(v.y >> 16));
    int e0 = off[w], e1 = off[w + 1];
    int e = e0;
    for (; e + 4 <= e1; e += 4) {
        int j0 = adj[e], j1 = adj[e + 1], j2 = adj[e + 2], j3 = adj[e + 3];
        uint2 u0 = *(const uint2*)(hp + (size_t)j0 * HID);
        uint2 u1 = *(const uint2*)(hp + (size_t)j1 * HID);
        uint2 u2 = *(const uint2*)(hp + (size_t)j2 * HID);
        uint2 u3 = *(const uint2*)(hp + (size_t)j3 * HID);
        s0 += bf2f((unsigned short)(u0.x & 0xffff)) + bf2f((unsigned short)(u1.x & 0xffff)) +
              bf2f((unsigned short)(u2.x & 0xffff)) + bf2f((unsigned short)(u3.x & 0xffff));
        s1 += bf2f((unsigned short)(u0.x >> 16)) + bf2f((unsigned short)(u1.x >> 16)) +
              bf2f((unsigned short)(u2.x >> 16)) + bf2f((unsigned short)(u3.x >> 16));
        s2 += bf2f((unsigned short)(u0.y & 0xffff)) + bf2f((unsigned short)(u1.y & 0xffff)) +
              bf2f((unsigned short)(u2.y & 0xffff)) + bf2f((unsigned short)(u3.y & 0xffff));
        s3 += bf2f((unsigned short)(u0.y >> 16)) + bf2f((unsigned short)(u1.y >> 16)) +
              bf2f((unsigned short)(u2.y >> 16)) + bf2f((unsigned short)(u3.y >> 16));
    }
    for (; e < e1; ++e) {
        uint2 u = *(const uint2*)(hp + (size_t)adj[e] * HID);
        s0 += bf2f((unsigned short)(u.x & 0xffff));
        s1 += bf2f((unsigned short)(u.x >> 16));
        s2 += bf2f((unsigned short)(u.y & 0xffff));
        s3 += bf2f((unsigned short)(u.y >> 16));
    }
    float dp1 = (float)(e1 - e0 + 1);
    float r0 = s0 * scl[0] + dp1 * shf[0];
    float r1 = s1 * scl[1] + dp1 * shf[1];
    float r2 = s2 * scl[2] + dp1 * shf[2];
    float r3 = s3 * scl[3] + dp1 * shf[3];
    unsigned long long o =
        (unsigned long long)((unsigned)f2bf(r0) | ((unsigned)f2bf(r1) << 16)) |
        ((unsigned long long)((unsigned)f2bf(r2) | ((unsigned)f2bf(r3) << 16)) << 32);
    __builtin_nontemporal_store(o, (unsigned long long*)(outb + (size_t)w * HID + fb));
}

// ---------- LDS-staged MFMA GEMM (m97 structure): Out[M,512] = act(A[M,K] @ W + bias) ----------
// A: bf16 row-major [M][K]. WT: bf16 transposed [512][K]. Tile 128x128, BK=64, 4 waves.
// Swizzle: 16B unit index u XOR (row&7), applied on global source & LDS read (rule 21).
template <int K, int ACT>
__global__ __launch_bounds__(256) void k_tgemm(const unsigned short* __restrict__ A,
                                               const unsigned short* __restrict__ WT,
                                               const float* __restrict__ bias,
                                               unsigned short* __restrict__ Out, int M) {
    constexpr int NC = 512;
    __shared__ __align__(16) char smem[32768];  // A:[0,16K) B:[16K,32K); epilogue C tile:[0,32K)
    const int tid = threadIdx.x;
    const int lane = tid & 63;
    const int w = tid >> 6;
    const int wm = w >> 1, wn = w & 1;
    const int l15 = lane & 15, lg = lane >> 4;
    const int rowbase = blockIdx.y * 128;
    const int colbase = blockIdx.x * 128;

    f32x4 acc[4][4];
#pragma unroll
    for (int i = 0; i < 4; ++i)
#pragma unroll
        for (int j = 0; j < 4; ++j) acc[i][j] = (f32x4)0.f;

    for (int k0 = 0; k0 < K; k0 += 64) {
        // stage A tile: 128 rows x 64 k (128B/row), source pre-swizzled
#pragma unroll
        for (int i = 0; i < 4; ++i) {
            int slot = i * 256 + tid;
            int r = slot >> 3;
            int u = (slot & 7) ^ (r & 7);
            int gr = rowbase + r; if (gr >= M) gr = M - 1;
            gl_lds16(A + (size_t)gr * K + k0 + u * 8, smem + (i * 256 + w * 64) * 16);
        }
        // stage B tile: 128 cols x 64 k from WT
#pragma unroll
        for (int i = 0; i < 4; ++i) {
            int slot = i * 256 + tid;
            int c = slot >> 3;
            int u = (slot & 7) ^ (c & 7);
            gl_lds16(WT + (size_t)(colbase + c) * K + k0 + u * 8,
                     smem + 16384 + (i * 256 + w * 64) * 16);
        }
        __syncthreads();
#pragma unroll
        for (int kin = 0; kin < 2; ++kin) {
            bf16x8 af[4], bfr[4];
#pragma unroll
            for (int mi = 0; mi < 4; ++mi) {
                int r = wm * 64 + mi * 16 + l15;
                int u = (kin * 4 + lg) ^ (r & 7);
                af[mi] = *(const bf16x8*)(smem + r * 128 + u * 16);
            }
#pragma unroll
            for (int ni = 0; ni < 4; ++ni) {
                int c = wn * 64 + ni * 16 + l15;
                int u = (kin * 4 + lg) ^ (c & 7);
                bfr[ni] = *(const bf16x8*)(smem + 16384 + c * 128 + u * 16);
            }
#pragma unroll
            for (int mi = 0; mi < 4; ++mi)
#pragma unroll
                for (int ni = 0; ni < 4; ++ni)
                    acc[mi][ni] = __builtin_amdgcn_mfma_f32_16x16x32_bf16(af[mi], bfr[ni], acc[mi][ni], 0, 0, 0);
        }
        __syncthreads();
    }

    // epilogue: bias+act -> LDS bf16 [128][128] (row-XOR swizzled) -> coalesced uint4 stores
#pragma unroll
    for (int ni = 0; ni < 4; ++ni) {
        int c = wn * 64 + ni * 16 + l15;
        float bv = bias[colbase + c];
#pragma unroll
        for (int mi = 0; mi < 4; ++mi) {
#pragma unroll
            for (int r = 0; r < 4; ++r) {
                int row = wm * 64 + mi * 16 + lg * 4 + r;
                float t = acc[mi][ni][r] + bv;
                t = (ACT == 0) ? fmaxf(t, 0.f) : selu_f(t);
                int byte = (row * 256 + c * 2) ^ ((row & 7) << 4);
                *(unsigned short*)(smem + byte) = f2bf(t);
            }
        }
    }
    __syncthreads();
#pragma unroll
    for (int it = 0; it < 8; ++it) {
        int idx = it * 256 + tid;
        int row = idx >> 4;
        int ch = idx & 15;
        int gr = rowbase + row;
        if (gr < M) {
            uint4 v = *(const uint4*)(smem + row * 256 + ((ch ^ (row & 7)) << 4));
            *(uint4*)(Out + (size_t)gr * NC + colbase + ch * 8) = v;
        }
    }
}

// ---------- register-direct MFMA GEMM (kept for the small final GEMM, f32 out) ----------
template <int K, int NC, int ACT, int WAVES_M, int WAVES_N, int NFRAG, typename TOUT>
__global__ __launch_bounds__(WAVES_M * WAVES_N * 64) void k_mgemm(
    const unsigned short* __restrict__ A, const unsigned short* __restrict__ Wp,
    const float* __restrict__ bias, TOUT* __restrict__ Out, int M) {
    const int tid = threadIdx.x;
    const int lane = tid & 63;
    const int w = tid >> 6;
    const int wm = w / WAVES_N;
    const int wn = w % WAVES_N;
    const int l15 = lane & 15;
    const int lg = lane >> 4;
    const int rowbase = blockIdx.x * (32 * WAVES_M) + wm * 32;
    const int colbase = blockIdx.y * (WAVES_N * 16 * NFRAG) + wn * 16 * NFRAG;
    int r0 = rowbase + l15; if (r0 > M - 1) r0 = M - 1;
    int r1 = rowbase + 16 + l15; if (r1 > M - 1) r1 = M - 1;
    const unsigned short* pa0 = A + (size_t)r0 * K + lg * 8;
    const unsigned short* pa1 = A + (size_t)r1 * K + lg * 8;
    const unsigned short* pw = Wp + (size_t)(colbase >> 4) * (K / 32) * 512 + lane * 8;

    f32x4 acc[2][NFRAG];
#pragma unroll
    for (int i = 0; i < 2; ++i)
#pragma unroll
        for (int j = 0; j < NFRAG; ++j) acc[i][j] = (f32x4)0.f;

#pragma unroll 2
    for (int kt = 0; kt < K / 32; ++kt) {
        bf16x8 a0 = *(const bf16x8*)(pa0 + kt * 32);
        bf16x8 a1 = *(const bf16x8*)(pa1 + kt * 32);
#pragma unroll
        for (int ni = 0; ni < NFRAG; ++ni) {
            bf16x8 bv = *(const bf16x8*)(pw + (ni * (K / 32) + kt) * 512);
            acc[0][ni] = __builtin_amdgcn_mfma_f32_16x16x32_bf16(a0, bv, acc[0][ni], 0, 0, 0);
            acc[1][ni] = __builtin_amdgcn_mfma_f32_16x16x32_bf16(a1, bv, acc[1][ni], 0, 0, 0);
        }
    }

#pragma unroll
    for (int ni = 0; ni < NFRAG; ++ni) {
        int c = colbase + ni * 16 + l15;
        float bv = bias[c];
#pragma unroll
        for (int mi = 0; mi < 2; ++mi) {
#pragma unroll
            for (int r = 0; r < 4; ++r) {
                int row = rowbase + mi * 16 + lg * 4 + r;
                if (row < M) {
                    float t = acc[mi][ni][r] + bv;
                    t = (ACT == 0) ? fmaxf(t, 0.f) : selu_f(t);
                    stb(&Out[(size_t)row * NC + c], t);
                }
            }
        }
    }
}

// ---------- BatchNorm stats ----------
__global__ __launch_bounds__(256) void k_bnstats_h(const unsigned short* __restrict__ C,
                                                   float* __restrict__ sums) {
    int t = threadIdx.x;  // features 2t, 2t+1
    float s0 = 0, q0 = 0, s1 = 0, q1 = 0;
    for (int r = blockIdx.x; r < N_NODES; r += gridDim.x) {
        unsigned v = ((const unsigned*)(C + (size_t)r * HID))[t];
        float a = bf2f((unsigned short)(v & 0xffff));
        float b = bf2f((unsigned short)(v >> 16));
        s0 += a; q0 += a * a;
        s1 += b; q1 += b * b;
    }
    atomicAdd(&sums[2 * t], s0);
    atomicAdd(&sums[2 * t + 1], s1);
    atomicAdd(&sums[HID + 2 * t], q0);
    atomicAdd(&sums[HID + 2 * t + 1], q1);
}

__global__ void k_bnprep(float* __restrict__ bn, const float* __restrict__ gamma,
                         const float* __restrict__ beta, int C, float invn) {
    int c = threadIdx.x + blockIdx.x * blockDim.x;
    if (c >= C) return;
    float mu = bn[c] * invn;
    float var = bn[C + c] * invn - mu * mu;
    float sc = gamma[c] * rsqrtf(var + 1e-5f);
    bn[2 * C + c] = sc;
    bn[3 * C + c] = beta[c] - mu * sc;
}

__global__ __launch_bounds__(256) void k_bnstats_o(const float* __restrict__ O,
                                                   float* __restrict__ bn2) {
    int t = threadIdx.x;
    int c = t & 63;
    int rr = t >> 6;
    float s = 0, q = 0;
    for (int r = blockIdx.x * 4 + rr; r < N_NODES; r += gridDim.x * 4) {
        float a = O[(size_t)r * NCLS + c];
        s += a; q += a * a;
    }
    atomicAdd(&bn2[c], s);
    atomicAdd(&bn2[NCLS + c], q);
}

__global__ __launch_bounds__(256) void k_softmax(float* __restrict__ O, const float* __restrict__ bn2) {
    int w = (blockIdx.x * 256 + threadIdx.x) >> 6;
    if (w >= N_NODES) return;
    int lane = threadIdx.x & 63;
    float z = O[(size_t)w * NCLS + lane] * bn2[2 * NCLS + lane] + bn2[3 * NCLS + lane];
    float m = z;
#pragma unroll
    for (int o = 32; o > 0; o >>= 1) m = fmaxf(m, __shfl_xor(m, o));
    float e = __expf(z - m);
    float s = e;
#pragma unroll
    for (int o = 32; o > 0; o >>= 1) s += __shfl_xor(s, o);
    O[(size_t)w * NCLS + lane] = e / s;
}

// ---------- launch ----------
extern "C" void kernel_launch(void* const* d_in, const int* in_sizes, int n_in,
                              void* d_out, int out_size, void* d_ws, size_t ws_size,
                              hipStream_t stream) {
    const float* x = (const float*)d_in[0];
    const int* edge = (const int*)d_in[1];
    const int* srcp = edge;
    const int* dstp = edge + N_EDGES;
    const float* W1a = (const float*)d_in[9];
    const float* b1a = (const float*)d_in[10];
    const float* W1b = (const float*)d_in[11];
    const float* b1b = (const float*)d_in[12];
    const float* gamma1 = (const float*)d_in[13];
    const float* beta1 = (const float*)d_in[14];
    const float* W2a = (const float*)d_in[15];
    const float* b2a = (const float*)d_in[16];
    const float* W2b = (const float*)d_in[17];
    const float* b2b = (const float*)d_in[18];
    const float* gamma2 = (const float*)d_in[19];
    const float* beta2 = (const float*)d_in[20];
    float* out = (float*)d_out;

    char* ws = (char*)d_ws;
    size_t o = 0;
    auto alloc = [&](size_t bytes) -> char* {
        char* p = ws + o;
        o = (o + bytes + 255) & ~(size_t)255;
        return p;
    };
    int* off = (int*)alloc((N_NODES + 1) * sizeof(int));
    int* deg = (int*)alloc(N_NODES * sizeof(int));
    int* pos = (int*)alloc(N_NODES * sizeof(int));
    int* adj = (int*)alloc(N_EDGES * sizeof(int));
    int* part = (int*)alloc(SCAN_NB * sizeof(int));
    int* base = (int*)alloc(SCAN_NB * sizeof(int));
    float* bn1 = (float*)alloc(4 * HID * sizeof(float));
    float* bn2 = (float*)alloc(4 * NCLS * sizeof(float));
    unsigned short* WT1 = (unsigned short*)alloc((size_t)IN_DIM * HID * sizeof(unsigned short));
    unsigned short* WT2 = (unsigned short*)alloc((size_t)HID * HID * sizeof(unsigned short));
    unsigned short* WT3 = (unsigned short*)alloc((size_t)HID * HID * sizeof(unsigned short));
    unsigned short* Wp4 = (unsigned short*)alloc((size_t)HID * NCLS * sizeof(unsigned short));
    unsigned short* xb = (unsigned short*)alloc((size_t)N_NODES * IN_DIM * sizeof(unsigned short));
    unsigned short* A1 = (unsigned short*)alloc((size_t)N_NODES * IN_DIM * sizeof(unsigned short));
    unsigned short* B = (unsigned short*)alloc((size_t)N_NODES * HID * sizeof(unsigned short));
    unsigned short* C = (unsigned short*)alloc((size_t)N_NODES * HID * sizeof(unsigned short));

    hipMemsetAsync(deg, 0, N_NODES * sizeof(int), stream);
    hipMemsetAsync(bn1, 0, 2 * HID * sizeof(float), stream);
    hipMemsetAsync(bn2, 0, 2 * NCLS * sizeof(float), stream);

    int eb = (N_EDGES + 255) / 256;
    k_cast<<<(N_NODES * IN_DIM / 8 + 255) / 256, 256, 0, stream>>>(x, xb);
    k_deg<<<eb, 256, 0, stream>>>(dstp, deg);
    k_scan_part<<<SCAN_NB, 256, 0, stream>>>(deg, part);
    k_scan_mid<<<1, 128, 0, stream>>>(part, base, off);
    k_scan_fin<<<SCAN_NB, 256, 0, stream>>>(deg, base, off, pos);
    k_fill<<<eb, 256, 0, stream>>>(srcp, dstp, pos, adj);

    // weight packing (tiny)
    k_packT<<<(IN_DIM * HID) / 256, 256, 0, stream>>>(W1a, WT1, IN_DIM, HID);
    k_packT<<<(HID * HID) / 256, 256, 0, stream>>>(W1b, WT2, HID, HID);
    k_packT<<<(HID * HID) / 256, 256, 0, stream>>>(W2a, WT3, HID, HID);
    k_pack<<<(HID * NCLS) / 256, 256, 0, stream>>>(W2b, Wp4, HID, NCLS);

    int nwb = (N_NODES * 64 + 255) / 256;  // one wave per node
    int mb128 = (N_NODES + 127) / 128;     // 782

    // layer 1
    k_agg1<<<nwb, 256, 0, stream>>>(xb, off, adj, A1);
    k_tgemm<IN_DIM, 0><<<dim3(4, mb128), 256, 0, stream>>>(A1, WT1, b1a, B, N_NODES);
    k_tgemm<HID, 1><<<dim3(4, mb128), 256, 0, stream>>>(B, WT2, b1b, C, N_NODES);

    k_bnstats_h<<<1024, 256, 0, stream>>>(C, bn1);
    k_bnprep<<<2, 256, 0, stream>>>(bn1, gamma1, beta1, HID, 1.0f / N_NODES);

    // layer 2: feature-sliced gather with fused BN1
    k_aggbn2<<<dim3(nwb, 2), 256, 0, stream>>>(C, off, adj, bn1, B);

    k_tgemm<HID, 0><<<dim3(4, mb128), 256, 0, stream>>>(B, WT3, b2a, C, N_NODES);
    k_mgemm<HID, NCLS, 1, 8, 1, 4, float><<<dim3((N_NODES + 255) / 256, 1), 512, 0, stream>>>(C, Wp4, b2b, out, N_NODES);

    k_bnstats_o<<<1024, 256, 0, stream>>>(out, bn2);
    k_bnprep<<<1, 64, 0, stream>>>(bn2, gamma2, beta2, NCLS, 1.0f / N_NODES);
    k_softmax<<<nwb, 256, 0, stream>>>(out, bn2);
}